// Round 4
// baseline (259.721 us; speedup 1.0000x reference)
//
#include <hip/hip_runtime.h>

#define B_ 8
#define C_ 128
#define N_ 4096
#define SCALE 0.08838834764831845f   // 1/sqrt(128)

typedef __attribute__((ext_vector_type(8))) short short8;   // 8 bf16
typedef __attribute__((ext_vector_type(4))) short short4v;  // 4 bf16
typedef __attribute__((ext_vector_type(4))) float f32x4;    // MFMA C/D

__device__ inline float b2f(unsigned short u) {
    union { unsigned int i; float f; } v; v.i = ((unsigned int)u) << 16; return v.f;
}
__device__ inline unsigned short f2b(float f) {            // RNE bf16 round
    unsigned int x = __float_as_uint(f);
    return (unsigned short)((x + 0x7FFFu + ((x >> 16) & 1u)) >> 16);
}

// async global->LDS, 16B per lane (m97 staging path).
__device__ inline void gld_lds16(const void* g, void* l) {
    __builtin_amdgcn_global_load_lds(
        (const __attribute__((address_space(1))) unsigned int*)g,
        (__attribute__((address_space(3))) unsigned int*)l, 16, 0, 0);
}

// 16x16x16 bf16 MFMA (K=16): builtin if present, else raw asm (gfx950 has
// v_mfma_f32_16x16x16_bf16 per ISA; A/B = 4 bf16 = 2 VGPRs).
#if __has_builtin(__builtin_amdgcn_mfma_f32_16x16x16bf16_1k)
__device__ inline f32x4 mfma16(short4v a, short4v b, f32x4 c) {
    return __builtin_amdgcn_mfma_f32_16x16x16bf16_1k(a, b, c, 0, 0, 0);
}
#elif __has_builtin(__builtin_amdgcn_mfma_f32_16x16x16_bf16)
__device__ inline f32x4 mfma16(short4v a, short4v b, f32x4 c) {
    return __builtin_amdgcn_mfma_f32_16x16x16_bf16(a, b, c, 0, 0, 0);
}
#else
__device__ inline f32x4 mfma16(short4v a, short4v b, f32x4 c) {
    asm("v_mfma_f32_16x16x16_bf16 %0, %1, %2, %0" : "+v"(c) : "v"(a), "v"(b));
    return c;
}
#endif

// ---------------------------------------------------------------------------
// MFMA QKV projection — EXACT R0 monolithic kernel (proven 76.6 us; the
// pass-split (1536 blk) and o-halved (1024 blk) variants both regressed ->
// qkv is not occupancy-limited; keep the proven structure).
//  - pass order q -> v -> k, W A-frags of the NEXT pass prefetched before the
//    current pass's 32 MFMAs.
//  - q and v store DIRECTLY from C/D regs; only k keeps the Obuf epilogue.
// kTs bf16 [b][n][o'] o-blocks ^ (n&15). vS bf16 [b][o][n'] 32-key windows,
// block' ^= (o>>1)&3. XCD map b = bid&7.
// mfma_f32_16x16x32_bf16: A[m=l15][k=quad*8+j]; B[k][n=l15];
// C/D row=quad*4+r, col=l15 (R6-R11 proven).
// ---------------------------------------------------------------------------
__global__ __launch_bounds__(256) void qkv_mfma(
    const float* __restrict__ x,
    const float* __restrict__ Wq, const float* __restrict__ bq,
    const float* __restrict__ Wk, const float* __restrict__ bk,
    const float* __restrict__ Wv, const float* __restrict__ bv,
    float* __restrict__ q, unsigned short* __restrict__ kTs,
    unsigned short* __restrict__ vS)
{
    __shared__ __align__(16) short Xs[64 * 128];    // 16 KB bf16 X^T, swizzled
    __shared__ __align__(16) float Obuf[64 * 132];  // 33.8 KB k-epilogue

    const int t    = threadIdx.x;
    const int w    = t >> 6;
    const int lane = t & 63;
    const int l15  = lane & 15;
    const int quad = lane >> 4;

    const int b  = blockIdx.x & 7;               // XCD-pinned batch
    const int n0 = (blockIdx.x >> 3) * 64;
    const long base = (long)b * C_ * N_;

    auto load_af = [&](const float* __restrict__ W, short8 (&af)[2][4]) {
        #pragma unroll
        for (int ot = 0; ot < 2; ++ot) {
            const int o = 32 * w + 16 * ot + l15;
            #pragma unroll
            for (int ks = 0; ks < 4; ++ks) {
                const float4 a0 = *(const float4*)(const void*)(W + o * C_ + ks * 32 + quad * 8);
                const float4 a1 = *(const float4*)(const void*)(W + o * C_ + ks * 32 + quad * 8 + 4);
                short8 f;
                f[0] = (short)f2b(a0.x); f[1] = (short)f2b(a0.y);
                f[2] = (short)f2b(a0.z); f[3] = (short)f2b(a0.w);
                f[4] = (short)f2b(a1.x); f[5] = (short)f2b(a1.y);
                f[6] = (short)f2b(a1.z); f[7] = (short)f2b(a1.w);
                af[ot][ks] = f;
            }
        }
    };

    auto mfma_pass = [&](const short8 (&af)[2][4], f32x4 (&acc)[2][4]) {
        #pragma unroll
        for (int ot = 0; ot < 2; ++ot)
            #pragma unroll
            for (int nt = 0; nt < 4; ++nt)
                acc[ot][nt] = (f32x4){0.f, 0.f, 0.f, 0.f};
        #pragma unroll
        for (int nt = 0; nt < 4; ++nt) {
            const int n = nt * 16 + l15;
            short8 bx[4];
            #pragma unroll
            for (int ks = 0; ks < 4; ++ks)
                bx[ks] = *(const short8*)(const void*)(Xs + n * 128 + (((ks * 4 + quad) ^ l15) << 3));
            #pragma unroll
            for (int ot = 0; ot < 2; ++ot)
                #pragma unroll
                for (int ks = 0; ks < 4; ++ks)
                    acc[ot][nt] = __builtin_amdgcn_mfma_f32_16x16x32_bf16(af[ot][ks], bx[ks], acc[ot][nt], 0, 0, 0);
        }
    };

    // ---- W(q) A-frags first, then stage X^T tile ----
    short8 afA[2][4], afB[2][4];
    load_af(Wq, afA);

    #pragma unroll
    for (int it = 0; it < 8; ++it) {
        const int c  = (t >> 4) + it * 16;
        const int n4 = (t & 15) * 4;
        const float4 xv = *(const float4*)(const void*)(x + base + (long)c * N_ + n0 + n4);
        const int bc = c >> 3, cl = c & 7;
        Xs[(n4 + 0) * 128 + ((bc ^ ((n4 + 0) & 15)) << 3) + cl] = (short)f2b(xv.x);
        Xs[(n4 + 1) * 128 + ((bc ^ ((n4 + 1) & 15)) << 3) + cl] = (short)f2b(xv.y);
        Xs[(n4 + 2) * 128 + ((bc ^ ((n4 + 2) & 15)) << 3) + cl] = (short)f2b(xv.z);
        Xs[(n4 + 3) * 128 + ((bc ^ ((n4 + 3) & 15)) << 3) + cl] = (short)f2b(xv.w);
    }
    __syncthreads();

    { // ======== pass 1: q -> d_out fp32 [b][o][n], pre-scaled ========
        load_af(Wv, afB);                          // prefetch v weights
        f32x4 acc[2][4];
        mfma_pass(afA, acc);
        #pragma unroll
        for (int ot = 0; ot < 2; ++ot)
            #pragma unroll
            for (int r = 0; r < 4; ++r) {
                const int o = 32 * w + 16 * ot + quad * 4 + r;
                const float bb = bq[o];
                #pragma unroll
                for (int nt = 0; nt < 4; ++nt)
                    q[base + (long)o * N_ + n0 + nt * 16 + l15] = (acc[ot][nt][r] + bb) * SCALE;
            }
    }

    { // ======== pass 2: v -> vS bf16, direct swizzled store ========
        load_af(Wk, afA);                          // prefetch k weights
        f32x4 acc[2][4];
        mfma_pass(afB, acc);
        #pragma unroll
        for (int ot = 0; ot < 2; ++ot)
            #pragma unroll
            for (int r = 0; r < 4; ++r) {
                const int o = 32 * w + 16 * ot + quad * 4 + r;
                const float bb = bv[o];
                const int sw = ((o >> 1) & 3) << 3;
                #pragma unroll
                for (int nt = 0; nt < 4; ++nt) {
                    const int n = nt * 16 + l15;
                    const int ns = (n & 32) | ((((n >> 3) & 3) << 3) ^ sw) | (n & 7);
                    vS[base + (long)o * N_ + n0 + ns] = f2b(acc[ot][nt][r] + bb);
                }
            }
    }

    { // ======== pass 3: k -> kTs bf16 [b][n][o'] via Obuf (stride 132) ========
        f32x4 acc[2][4];
        mfma_pass(afA, acc);
        #pragma unroll
        for (int ot = 0; ot < 2; ++ot)
            #pragma unroll
            for (int r = 0; r < 4; ++r) {
                const int o = 32 * w + 16 * ot + quad * 4 + r;
                const float bb = bk[o];
                #pragma unroll
                for (int nt = 0; nt < 4; ++nt) {
                    const int n = nt * 16 + l15;
                    Obuf[n * 132 + (((o >> 3) ^ l15) << 3) + (o & 7)] = acc[ot][nt][r] + bb;
                }
            }
        __syncthreads();
        const int n = t >> 2, oh = (t & 3) * 32;
        #pragma unroll
        for (int i = 0; i < 32; i += 4) {
            const float4 kv = *(const float4*)(const void*)(Obuf + n * 132 + oh + i);
            short4v s;
            s[0] = (short)f2b(kv.x); s[1] = (short)f2b(kv.y);
            s[2] = (short)f2b(kv.z); s[3] = (short)f2b(kv.w);
            *(short4v*)(void*)(kTs + base + (long)(n0 + n) * C_ + oh + i) = s;
        }
    }
}

// ---------------------------------------------------------------------------
// MFMA flash attention + residual, R16: P NEVER TOUCHES LDS.
//  - Swapped QK: mfma(A=kf, B=qf) — same per-lane fragments as before (A and
//    B frag lane layouts coincide), output transposed: lane (quad,l15) holds
//    P[key=quad*4+r][query=l15] for its h-half 16-key block.
//  - That per-lane key set IS the A-frag of mfma_16x16x16 PV
//    (A[m=query l15][k=key quad*4+j]) — zero cross-lane movement:
//    exp -> v_cvt_pk_bf16_f32 -> PV directly from registers.
//  - h now splits KEYS (16 each); each wave computes all 128 ch for its 32
//    queries: acc[qh][ct] = 32q x 128c. V read as b64 (4 keys), shared
//    across both qh. Row-sums = per-lane adds of rounded P (keeps R0-R3
//    numerics; no ones-MFMA).
//  - Deleted per wave-iter: 8 ds_write_b16, 2 ds_read_b128, 8 f2b, the
//    P lgkmcnt hinge. Kept: 1 barrier/iter, counted vmcnt(4), V dbuf,
//    kf global prefetch, setprio (T5).
//  - Merge is 4-way (g x h): two Ot h-planes, g0 writes / g1 adds, final
//    sums planes. LDS ~71KB -> 2 blocks/CU. launch_bounds(512,4) pins
//    VGPR <= 128 (occupancy cliff guard).
// ---------------------------------------------------------------------------
__global__ __launch_bounds__(512, 4) void attn_mfma(
    const float* qg,                  // aliases out (q written by qkv, fp32)
    const unsigned short* __restrict__ kTs,
    const unsigned short* __restrict__ vS,
    const float* __restrict__ xg,
    float* out)
{
    __shared__ __align__(16) union {
        short V[2][2][4096];          // [buf][grp][128 ch x 32 keys] swizzled
        float Ot[2][64][130];         // [h-plane][query][ch] epilogue merge
    } sm;
    __shared__ float Ls2[2][2][4][4][16]; // [g][h][quad][wq*2+qh][l15]
    __shared__ float linvA[64];

    const int t    = threadIdx.x;
    const int w    = t >> 6;          // 0..7
    const int g    = w >> 2;          // key-group (2048-key half)
    const int wq   = (w >> 1) & 1;    // 32-query subtile
    const int h    = w & 1;           // 16-key half of the 32-key group tile
    const int sub  = w & 3;           // staging sub-tile
    const int lane = t & 63;
    const int l15  = lane & 15;
    const int quad = lane >> 4;

    const int b  = blockIdx.x & 7;               // XCD-pinned batch
    const int n0 = (blockIdx.x >> 3) * 64;
    const long base = (long)b * C_ * N_;

    // ---- Q frags: 32 queries per wave (2 x 16q subtiles), used as B-operand
    // (B[k=c quad*8+j][n=query l15] — same per-lane gather as the A-frag) ----
    const int query0 = n0 + 32 * wq;
    short8 qf[2][4];
    #pragma unroll
    for (int qh = 0; qh < 2; ++qh)
        #pragma unroll
        for (int ks = 0; ks < 4; ++ks) {
            short8 f;
            #pragma unroll
            for (int j = 0; j < 8; ++j) {
                const int c = ks * 32 + quad * 8 + j;
                f[j] = (short)f2b(qg[base + (long)c * N_ + query0 + qh * 16 + l15]);
            }
            qf[qh][ks] = f;
        }

    f32x4 acc[2][8];                  // [qh][ct]: 32q x 128c
    #pragma unroll
    for (int qh = 0; qh < 2; ++qh)
        #pragma unroll
        for (int ct = 0; ct < 8; ++ct) acc[qh][ct] = (f32x4){0.f, 0.f, 0.f, 0.f};
    float accSp[2] = {0.f, 0.f};      // per-lane row-sum partials (query l15)

    auto stageV = [&](int buf, int pair) {       // exactly 2 VMEM ops / lane
        const int mt = pair * 2 + g;
        char* lV = (char*)sm.V[buf][g];
        #pragma unroll
        for (int jj = 0; jj < 2; ++jj) {
            const int d  = sub * 2048 + jj * 1024;
            const int dv = d + lane * 16;
            const int c  = dv >> 6;
            gld_lds16((const char*)(vS + base + (long)c * N_ + mt * 32) + (dv & 63), lV + d);
        }
    };

    // ---- K direct global->reg as A-frag: A[m=key l15][k=c quad*8+j];
    // key = mt*32 + h*16 + l15, key&15 == l15 so kTs swizzle inverts ----
    const unsigned short* kp = kTs + base + (long)((g * 32 + h * 16 + l15) * C_);
    int ko[4];
    #pragma unroll
    for (int ks = 0; ks < 4; ++ks) ko[ks] = (((ks * 4 + quad) ^ l15) << 3);
    short8 kf[4];

    #pragma unroll
    for (int ks = 0; ks < 4; ++ks) kf[ks] = *(const short8*)(const void*)(kp + ko[ks]);
    kp += 64 * C_;
    stageV(0, 0);

    for (int i = 0; i < 64; ++i) {
        // ---- swapped QK (registers only): C[key=quad*4+r][query=l15] ----
        f32x4 sc[2];
        sc[0] = (f32x4){0.f, 0.f, 0.f, 0.f};
        sc[1] = (f32x4){0.f, 0.f, 0.f, 0.f};
        __builtin_amdgcn_s_setprio(1);
        #pragma unroll
        for (int ks = 0; ks < 4; ++ks) {
            sc[0] = __builtin_amdgcn_mfma_f32_16x16x32_bf16(kf[ks], qf[0][ks], sc[0], 0, 0, 0);
            sc[1] = __builtin_amdgcn_mfma_f32_16x16x32_bf16(kf[ks], qf[1][ks], sc[1], 0, 0, 0);
        }
        __builtin_amdgcn_s_setprio(0);

        // ---- prefetch kf(i+1): ~full iteration in flight (L2) ----
        if (i < 63) {
            #pragma unroll
            for (int ks = 0; ks < 4; ++ks) kf[ks] = *(const short8*)(const void*)(kp + ko[ks]);
            kp += 64 * C_;
        }

        // ---- exp -> packed bf16 P (in registers); row-sum of ROUNDED P ----
        short4v pa[2];
        #pragma unroll
        for (int qh = 0; qh < 2; ++qh) {
            const float e0 = __expf(sc[qh][0]);
            const float e1 = __expf(sc[qh][1]);
            const float e2 = __expf(sc[qh][2]);
            const float e3 = __expf(sc[qh][3]);
            unsigned int w0, w1;
            asm("v_cvt_pk_bf16_f32 %0, %1, %2" : "=v"(w0) : "v"(e0), "v"(e1));
            asm("v_cvt_pk_bf16_f32 %0, %1, %2" : "=v"(w1) : "v"(e2), "v"(e3));
            accSp[qh] += (__uint_as_float(w0 << 16) + __uint_as_float(w0 & 0xFFFF0000u))
                       + (__uint_as_float(w1 << 16) + __uint_as_float(w1 & 0xFFFF0000u));
            union { unsigned int u[2]; short4v s; } pk;
            pk.u[0] = w0; pk.u[1] = w1;
            pa[qh] = pk.s;
        }

        // ---- single sync point: drain own stageV(i) (kf(i+1) stays in
        // flight), then barrier -> V(i) visible ----
        if (i < 63) asm volatile("s_waitcnt vmcnt(4)" ::: "memory");
        else        asm volatile("s_waitcnt vmcnt(0)" ::: "memory");
        __builtin_amdgcn_s_barrier();
        __builtin_amdgcn_sched_barrier(0);
        if (i < 63) stageV((i + 1) & 1, i + 1);

        // ---- PV from registers: 16x16x16, V as b64 (4 keys), shared qh ----
        const short* Vb = sm.V[i & 1][g];
        const int vbk = h * 2 + (quad >> 1);
        const int vof = (quad & 1) << 2;
        __builtin_amdgcn_s_setprio(1);
        #pragma unroll
        for (int ct = 0; ct < 8; ++ct) {
            const int ch = ct * 16 + l15;
            const short4v vf = *(const short4v*)(const void*)(
                Vb + ch * 32 + ((vbk ^ ((l15 >> 1) & 3)) << 3) + vof);
            acc[0][ct] = mfma16(pa[0], vf, acc[0][ct]);
            acc[1][ct] = mfma16(pa[1], vf, acc[1][ct]);
        }
        __builtin_amdgcn_s_setprio(0);
    }

    // ---- merge epilogue: 4-way (g x h) via two Ot planes ----
    __syncthreads();                  // all PV reads consumed; union reusable
    #pragma unroll
    for (int qh = 0; qh < 2; ++qh)
        Ls2[g][h][quad][wq * 2 + qh][l15] = accSp[qh];
    if (g == 0) {
        #pragma unroll
        for (int qh = 0; qh < 2; ++qh)
            #pragma unroll
            for (int ct = 0; ct < 8; ++ct)
                #pragma unroll
                for (int r = 0; r < 4; ++r)
                    sm.Ot[h][32 * wq + qh * 16 + quad * 4 + r][ct * 16 + l15] = acc[qh][ct][r];
    }
    __syncthreads();
    if (g == 1) {
        #pragma unroll
        for (int qh = 0; qh < 2; ++qh)
            #pragma unroll
            for (int ct = 0; ct < 8; ++ct)
                #pragma unroll
                for (int r = 0; r < 4; ++r)
                    sm.Ot[h][32 * wq + qh * 16 + quad * 4 + r][ct * 16 + l15] += acc[qh][ct][r];
    } else if (t < 64) {
        float s = 0.f;
        #pragma unroll
        for (int gg = 0; gg < 2; ++gg)
            #pragma unroll
            for (int hh = 0; hh < 2; ++hh)
                #pragma unroll
                for (int qq = 0; qq < 4; ++qq)
                    s += Ls2[gg][hh][qq][t >> 4][t & 15];
        linvA[t] = 1.0f / fmaxf(s, 1e-20f);
    }
    __syncthreads();

    const int c  = t >> 2;
    const int nh = (t & 3) * 16;
    const long gb = base + (long)c * N_ + n0 + nh;
    #pragma unroll
    for (int i = 0; i < 16; i += 4) {
        const float4 xs = *(const float4*)(const void*)(xg + gb + i);
        float4 rv;
        rv.x = (sm.Ot[0][nh + i + 0][c] + sm.Ot[1][nh + i + 0][c]) * linvA[nh + i + 0] + xs.x;
        rv.y = (sm.Ot[0][nh + i + 1][c] + sm.Ot[1][nh + i + 1][c]) * linvA[nh + i + 1] + xs.y;
        rv.z = (sm.Ot[0][nh + i + 2][c] + sm.Ot[1][nh + i + 2][c]) * linvA[nh + i + 2] + xs.z;
        rv.w = (sm.Ot[0][nh + i + 3][c] + sm.Ot[1][nh + i + 3][c]) * linvA[nh + i + 3] + xs.w;
        *(float4*)(void*)(out + gb + i) = rv;
    }
}

// ---------------------------------------------------------------------------
extern "C" void kernel_launch(void* const* d_in, const int* in_sizes, int n_in,
                              void* d_out, int out_size, void* d_ws, size_t ws_size,
                              hipStream_t stream) {
    const float* x  = (const float*)d_in[0];
    const float* Wq = (const float*)d_in[1];
    const float* bq = (const float*)d_in[2];
    const float* Wk = (const float*)d_in[3];
    const float* bk = (const float*)d_in[4];
    const float* Wv = (const float*)d_in[5];
    const float* bv = (const float*)d_in[6];
    float* out = (float*)d_out;

    const long BCN = (long)B_ * C_ * N_;                  // 4,194,304
    unsigned short* kTs = (unsigned short*)d_ws;          // [b][n][o'] bf16 swizzled
    unsigned short* vS  = kTs + BCN;                      // [b][o][n'] bf16 swizzled

    // q lives in d_out [b][c][n] fp32 (pre-scaled): each attn block reads only
    // its own query columns and overwrites exactly those columns at the end.
    qkv_mfma<<<512, 256, 0, stream>>>(x, Wq, bq, Wk, bk, Wv, bv, out, kTs, vS);
    attn_mfma<<<B_ * (N_ / 64), 512, 0, stream>>>(out, kTs, vS, x, out);
}

// Round 5
// 233.593 us; speedup vs baseline: 1.1119x; 1.1119x over previous
//
#include <hip/hip_runtime.h>

#define B_ 8
#define C_ 128
#define N_ 4096
#define SCALE 0.08838834764831845f   // 1/sqrt(128)

typedef __attribute__((ext_vector_type(8))) short short8;   // 8 bf16
typedef __attribute__((ext_vector_type(4))) short short4v;  // 4 bf16
typedef __attribute__((ext_vector_type(4))) float f32x4;    // MFMA C/D

__device__ inline float b2f(unsigned short u) {
    union { unsigned int i; float f; } v; v.i = ((unsigned int)u) << 16; return v.f;
}
__device__ inline unsigned short f2b(float f) {            // RNE bf16 round
    unsigned int x = __float_as_uint(f);
    return (unsigned short)((x + 0x7FFFu + ((x >> 16) & 1u)) >> 16);
}

// async global->LDS, 16B per lane (m97 staging path).
__device__ inline void gld_lds16(const void* g, void* l) {
    __builtin_amdgcn_global_load_lds(
        (const __attribute__((address_space(1))) unsigned int*)g,
        (__attribute__((address_space(3))) unsigned int*)l, 16, 0, 0);
}

// 16x16x16 bf16 MFMA (K=16): builtin if present, else raw asm (gfx950 has
// v_mfma_f32_16x16x16_bf16 per ISA; A/B = 4 bf16 = 2 VGPRs).
#if __has_builtin(__builtin_amdgcn_mfma_f32_16x16x16bf16_1k)
__device__ inline f32x4 mfma16(short4v a, short4v b, f32x4 c) {
    return __builtin_amdgcn_mfma_f32_16x16x16bf16_1k(a, b, c, 0, 0, 0);
}
#elif __has_builtin(__builtin_amdgcn_mfma_f32_16x16x16_bf16)
__device__ inline f32x4 mfma16(short4v a, short4v b, f32x4 c) {
    return __builtin_amdgcn_mfma_f32_16x16x16_bf16(a, b, c, 0, 0, 0);
}
#else
__device__ inline f32x4 mfma16(short4v a, short4v b, f32x4 c) {
    asm("v_mfma_f32_16x16x16_bf16 %0, %1, %2, %0" : "+v"(c) : "v"(a), "v"(b));
    return c;
}
#endif

// ---------------------------------------------------------------------------
// MFMA QKV projection — EXACT R0 monolithic kernel (proven 76.6 us; pass-split
// and o-halved variants both regressed -> qkv is not occupancy-limited).
//  - pass order q -> v -> k, W A-frags of the NEXT pass prefetched before the
//    current pass's 32 MFMAs.
//  - q and v store DIRECTLY from C/D regs; only k keeps the Obuf epilogue.
// kTs bf16 [b][n][o'] o-blocks ^ (n&15). vS bf16 [b][o][n'] 32-key windows,
// block' ^= (o>>1)&3. XCD map b = bid&7.
// mfma_f32_16x16x32_bf16: A[m=l15][k=quad*8+j]; B[k][n=l15];
// C/D row=quad*4+r, col=l15 (R6-R11 proven).
// ---------------------------------------------------------------------------
__global__ __launch_bounds__(256) void qkv_mfma(
    const float* __restrict__ x,
    const float* __restrict__ Wq, const float* __restrict__ bq,
    const float* __restrict__ Wk, const float* __restrict__ bk,
    const float* __restrict__ Wv, const float* __restrict__ bv,
    float* __restrict__ q, unsigned short* __restrict__ kTs,
    unsigned short* __restrict__ vS)
{
    __shared__ __align__(16) short Xs[64 * 128];    // 16 KB bf16 X^T, swizzled
    __shared__ __align__(16) float Obuf[64 * 132];  // 33.8 KB k-epilogue

    const int t    = threadIdx.x;
    const int w    = t >> 6;
    const int lane = t & 63;
    const int l15  = lane & 15;
    const int quad = lane >> 4;

    const int b  = blockIdx.x & 7;               // XCD-pinned batch
    const int n0 = (blockIdx.x >> 3) * 64;
    const long base = (long)b * C_ * N_;

    auto load_af = [&](const float* __restrict__ W, short8 (&af)[2][4]) {
        #pragma unroll
        for (int ot = 0; ot < 2; ++ot) {
            const int o = 32 * w + 16 * ot + l15;
            #pragma unroll
            for (int ks = 0; ks < 4; ++ks) {
                const float4 a0 = *(const float4*)(const void*)(W + o * C_ + ks * 32 + quad * 8);
                const float4 a1 = *(const float4*)(const void*)(W + o * C_ + ks * 32 + quad * 8 + 4);
                short8 f;
                f[0] = (short)f2b(a0.x); f[1] = (short)f2b(a0.y);
                f[2] = (short)f2b(a0.z); f[3] = (short)f2b(a0.w);
                f[4] = (short)f2b(a1.x); f[5] = (short)f2b(a1.y);
                f[6] = (short)f2b(a1.z); f[7] = (short)f2b(a1.w);
                af[ot][ks] = f;
            }
        }
    };

    auto mfma_pass = [&](const short8 (&af)[2][4], f32x4 (&acc)[2][4]) {
        #pragma unroll
        for (int ot = 0; ot < 2; ++ot)
            #pragma unroll
            for (int nt = 0; nt < 4; ++nt)
                acc[ot][nt] = (f32x4){0.f, 0.f, 0.f, 0.f};
        #pragma unroll
        for (int nt = 0; nt < 4; ++nt) {
            const int n = nt * 16 + l15;
            short8 bx[4];
            #pragma unroll
            for (int ks = 0; ks < 4; ++ks)
                bx[ks] = *(const short8*)(const void*)(Xs + n * 128 + (((ks * 4 + quad) ^ l15) << 3));
            #pragma unroll
            for (int ot = 0; ot < 2; ++ot)
                #pragma unroll
                for (int ks = 0; ks < 4; ++ks)
                    acc[ot][nt] = __builtin_amdgcn_mfma_f32_16x16x32_bf16(af[ot][ks], bx[ks], acc[ot][nt], 0, 0, 0);
        }
    };

    // ---- W(q) A-frags first, then stage X^T tile ----
    short8 afA[2][4], afB[2][4];
    load_af(Wq, afA);

    #pragma unroll
    for (int it = 0; it < 8; ++it) {
        const int c  = (t >> 4) + it * 16;
        const int n4 = (t & 15) * 4;
        const float4 xv = *(const float4*)(const void*)(x + base + (long)c * N_ + n0 + n4);
        const int bc = c >> 3, cl = c & 7;
        Xs[(n4 + 0) * 128 + ((bc ^ ((n4 + 0) & 15)) << 3) + cl] = (short)f2b(xv.x);
        Xs[(n4 + 1) * 128 + ((bc ^ ((n4 + 1) & 15)) << 3) + cl] = (short)f2b(xv.y);
        Xs[(n4 + 2) * 128 + ((bc ^ ((n4 + 2) & 15)) << 3) + cl] = (short)f2b(xv.z);
        Xs[(n4 + 3) * 128 + ((bc ^ ((n4 + 3) & 15)) << 3) + cl] = (short)f2b(xv.w);
    }
    __syncthreads();

    { // ======== pass 1: q -> d_out fp32 [b][o][n], pre-scaled ========
        load_af(Wv, afB);                          // prefetch v weights
        f32x4 acc[2][4];
        mfma_pass(afA, acc);
        #pragma unroll
        for (int ot = 0; ot < 2; ++ot)
            #pragma unroll
            for (int r = 0; r < 4; ++r) {
                const int o = 32 * w + 16 * ot + quad * 4 + r;
                const float bb = bq[o];
                #pragma unroll
                for (int nt = 0; nt < 4; ++nt)
                    q[base + (long)o * N_ + n0 + nt * 16 + l15] = (acc[ot][nt][r] + bb) * SCALE;
            }
    }

    { // ======== pass 2: v -> vS bf16, direct swizzled store ========
        load_af(Wk, afA);                          // prefetch k weights
        f32x4 acc[2][4];
        mfma_pass(afB, acc);
        #pragma unroll
        for (int ot = 0; ot < 2; ++ot)
            #pragma unroll
            for (int r = 0; r < 4; ++r) {
                const int o = 32 * w + 16 * ot + quad * 4 + r;
                const float bb = bv[o];
                const int sw = ((o >> 1) & 3) << 3;
                #pragma unroll
                for (int nt = 0; nt < 4; ++nt) {
                    const int n = nt * 16 + l15;
                    const int ns = (n & 32) | ((((n >> 3) & 3) << 3) ^ sw) | (n & 7);
                    vS[base + (long)o * N_ + n0 + ns] = f2b(acc[ot][nt][r] + bb);
                }
            }
    }

    { // ======== pass 3: k -> kTs bf16 [b][n][o'] via Obuf (stride 132) ========
        f32x4 acc[2][4];
        mfma_pass(afA, acc);
        #pragma unroll
        for (int ot = 0; ot < 2; ++ot)
            #pragma unroll
            for (int r = 0; r < 4; ++r) {
                const int o = 32 * w + 16 * ot + quad * 4 + r;
                const float bb = bk[o];
                #pragma unroll
                for (int nt = 0; nt < 4; ++nt) {
                    const int n = nt * 16 + l15;
                    Obuf[n * 132 + (((o >> 3) ^ l15) << 3) + (o & 7)] = acc[ot][nt][r] + bb;
                }
            }
        __syncthreads();
        const int n = t >> 2, oh = (t & 3) * 32;
        #pragma unroll
        for (int i = 0; i < 32; i += 4) {
            const float4 kv = *(const float4*)(const void*)(Obuf + n * 132 + oh + i);
            short4v s;
            s[0] = (short)f2b(kv.x); s[1] = (short)f2b(kv.y);
            s[2] = (short)f2b(kv.z); s[3] = (short)f2b(kv.w);
            *(short4v*)(void*)(kTs + base + (long)(n0 + n) * C_ + oh + i) = s;
        }
    }
}

// ---------------------------------------------------------------------------
// MFMA flash attention + residual, R17: P-in-registers WITHOUT the spill.
// R16 blew the 128-VGPR cap (acc 64 + qf 32 + kf 16 ~ 140 -> scratch;
// WRITE_SIZE 17.4->36.9MB). Wave roles now (g, wq in 0..3): 16 queries x
// 32 keys x 128 channels per wave:
//   acc = 16q x 128c = 8 f32x4 = 32 VGPR; qf 16; kf[kt=2][4] = 32;
//   total ~111 < 128 -> fits.
//  - Swapped QK per key-tile kt: mfma32(A=kf[kt], B=qf) -> lane (quad,l15)
//    holds P[key=kt*16+quad*4+r][query=l15] — the A-frag of mfma16 PV.
//  - exp -> v_cvt_pk_bf16_f32 -> PV from registers; row-sum = per-lane adds
//    of ROUNDED P (bit-extract from packed words).
//  - V read as b64: key-block vbk = kt*2+(quad>>1), offset (quad&1)*4,
//    swizzle ^ (l15>>1)&3 (vS layout unchanged).
//  - Kept: 1 barrier/iter, counted vmcnt(8) (8 kf loads in flight across
//    the barrier, 2 stageV drained), V dbuf, kf global prefetch, setprio.
//  - Merge: 2-way (g) single Ot plane; row-sums via Ls[g][wq][quad][l15].
// ---------------------------------------------------------------------------
__global__ __launch_bounds__(512, 4) void attn_mfma(
    const float* qg,                  // aliases out (q written by qkv, fp32)
    const unsigned short* __restrict__ kTs,
    const unsigned short* __restrict__ vS,
    const float* __restrict__ xg,
    float* out)
{
    __shared__ __align__(16) union {
        short V[2][2][4096];          // [buf][grp][128 ch x 32 keys] swizzled
        float Ot[64][130];            // [query][ch] epilogue merge
    } sm;
    __shared__ float Ls[2][4][4][16]; // [g][wq][quad][l15] row-sum partials
    __shared__ float linvA[64];

    const int t    = threadIdx.x;
    const int w    = t >> 6;          // 0..7
    const int g    = w >> 2;          // key-group (2048-key half)
    const int wq   = w & 3;           // 16-query subtile
    const int lane = t & 63;
    const int l15  = lane & 15;
    const int quad = lane >> 4;

    const int b  = blockIdx.x & 7;               // XCD-pinned batch
    const int n0 = (blockIdx.x >> 3) * 64;
    const long base = (long)b * C_ * N_;

    // ---- Q frags: 16 queries per wave, used as B-operand
    // (B[k=c quad*8+j][n=query l15]) ----
    const int query0 = n0 + 16 * wq;
    short8 qf[4];
    #pragma unroll
    for (int ks = 0; ks < 4; ++ks) {
        short8 f;
        #pragma unroll
        for (int j = 0; j < 8; ++j) {
            const int c = ks * 32 + quad * 8 + j;
            f[j] = (short)f2b(qg[base + (long)c * N_ + query0 + l15]);
        }
        qf[ks] = f;
    }

    f32x4 acc[8];                     // [ct]: 16q x 128c
    #pragma unroll
    for (int ct = 0; ct < 8; ++ct) acc[ct] = (f32x4){0.f, 0.f, 0.f, 0.f};
    float accSp = 0.f;                // per-lane row-sum partial (query l15)

    auto stageV = [&](int buf, int pair) {       // exactly 2 VMEM ops / lane
        const int mt = pair * 2 + g;
        char* lV = (char*)sm.V[buf][g];
        #pragma unroll
        for (int jj = 0; jj < 2; ++jj) {
            const int d  = wq * 2048 + jj * 1024;
            const int dv = d + lane * 16;
            const int c  = dv >> 6;
            gld_lds16((const char*)(vS + base + (long)c * N_ + mt * 32) + (dv & 63), lV + d);
        }
    };

    // ---- K direct global->reg as A-frag: A[m=key l15][k=c quad*8+j];
    // key = mt*32 + kt*16 + l15, key&15 == l15 so kTs swizzle inverts ----
    const unsigned short* kp = kTs + base + (long)((g * 32 + l15) * C_);
    int ko[4];
    #pragma unroll
    for (int ks = 0; ks < 4; ++ks) ko[ks] = (((ks * 4 + quad) ^ l15) << 3);
    short8 kf[2][4];

    #pragma unroll
    for (int kt = 0; kt < 2; ++kt)
        #pragma unroll
        for (int ks = 0; ks < 4; ++ks)
            kf[kt][ks] = *(const short8*)(const void*)(kp + kt * 16 * C_ + ko[ks]);
    kp += 64 * C_;
    stageV(0, 0);

    for (int i = 0; i < 64; ++i) {
        // ---- swapped QK (registers only): C[key=kt*16+quad*4+r][query=l15] ----
        f32x4 sc[2];
        sc[0] = (f32x4){0.f, 0.f, 0.f, 0.f};
        sc[1] = (f32x4){0.f, 0.f, 0.f, 0.f};
        __builtin_amdgcn_s_setprio(1);
        #pragma unroll
        for (int ks = 0; ks < 4; ++ks) {
            sc[0] = __builtin_amdgcn_mfma_f32_16x16x32_bf16(kf[0][ks], qf[ks], sc[0], 0, 0, 0);
            sc[1] = __builtin_amdgcn_mfma_f32_16x16x32_bf16(kf[1][ks], qf[ks], sc[1], 0, 0, 0);
        }
        __builtin_amdgcn_s_setprio(0);

        // ---- prefetch kf(i+1): ~full iteration in flight (L2) ----
        if (i < 63) {
            #pragma unroll
            for (int kt = 0; kt < 2; ++kt)
                #pragma unroll
                for (int ks = 0; ks < 4; ++ks)
                    kf[kt][ks] = *(const short8*)(const void*)(kp + kt * 16 * C_ + ko[ks]);
            kp += 64 * C_;
        }

        // ---- exp -> packed bf16 P (registers); row-sum of ROUNDED P ----
        short4v pa[2];
        #pragma unroll
        for (int kt = 0; kt < 2; ++kt) {
            const float e0 = __expf(sc[kt][0]);
            const float e1 = __expf(sc[kt][1]);
            const float e2 = __expf(sc[kt][2]);
            const float e3 = __expf(sc[kt][3]);
            unsigned int w0, w1;
            asm("v_cvt_pk_bf16_f32 %0, %1, %2" : "=v"(w0) : "v"(e0), "v"(e1));
            asm("v_cvt_pk_bf16_f32 %0, %1, %2" : "=v"(w1) : "v"(e2), "v"(e3));
            accSp += (__uint_as_float(w0 << 16) + __uint_as_float(w0 & 0xFFFF0000u))
                   + (__uint_as_float(w1 << 16) + __uint_as_float(w1 & 0xFFFF0000u));
            union { unsigned int u[2]; short4v s; } pk;
            pk.u[0] = w0; pk.u[1] = w1;
            pa[kt] = pk.s;
        }

        // ---- single sync point: drain own stageV(i) (kf(i+1) stays in
        // flight: 8 newer loads), then barrier -> V(i) visible ----
        if (i < 63) asm volatile("s_waitcnt vmcnt(8)" ::: "memory");
        else        asm volatile("s_waitcnt vmcnt(0)" ::: "memory");
        __builtin_amdgcn_s_barrier();
        __builtin_amdgcn_sched_barrier(0);
        if (i < 63) stageV((i + 1) & 1, i + 1);

        // ---- PV from registers: mfma16 x16; V as b64 (4 keys/lane) ----
        const short* Vb = sm.V[i & 1][g];
        const int s3  = (l15 >> 1) & 3;
        const int vof = (quad & 1) << 2;
        __builtin_amdgcn_s_setprio(1);
        #pragma unroll
        for (int ct = 0; ct < 8; ++ct) {
            const int ch = ct * 16 + l15;
            const short4v vf0 = *(const short4v*)(const void*)(
                Vb + ch * 32 + ((((quad >> 1)) ^ s3) << 3) + vof);
            const short4v vf1 = *(const short4v*)(const void*)(
                Vb + ch * 32 + (((2 + (quad >> 1)) ^ s3) << 3) + vof);
            acc[ct] = mfma16(pa[0], vf0, acc[ct]);
            acc[ct] = mfma16(pa[1], vf1, acc[ct]);
        }
        __builtin_amdgcn_s_setprio(0);
    }

    // ---- merge epilogue: 2-way (g), single Ot plane ----
    Ls[g][wq][quad][l15] = accSp;
    __syncthreads();                  // all PV reads consumed; union reusable
    if (g == 0) {
        #pragma unroll
        for (int ct = 0; ct < 8; ++ct)
            #pragma unroll
            for (int r = 0; r < 4; ++r)
                sm.Ot[16 * wq + quad * 4 + r][ct * 16 + l15] = acc[ct][r];
    }
    __syncthreads();
    if (g == 1) {
        #pragma unroll
        for (int ct = 0; ct < 8; ++ct)
            #pragma unroll
            for (int r = 0; r < 4; ++r)
                sm.Ot[16 * wq + quad * 4 + r][ct * 16 + l15] += acc[ct][r];
    } else if (t < 64) {
        float s = 0.f;
        #pragma unroll
        for (int gg = 0; gg < 2; ++gg)
            #pragma unroll
            for (int qq = 0; qq < 4; ++qq)
                s += Ls[gg][t >> 4][qq][t & 15];
        linvA[t] = 1.0f / fmaxf(s, 1e-20f);
    }
    __syncthreads();

    const int c  = t >> 2;
    const int nh = (t & 3) * 16;
    const long gb = base + (long)c * N_ + n0 + nh;
    #pragma unroll
    for (int i = 0; i < 16; i += 4) {
        const float4 xs = *(const float4*)(const void*)(xg + gb + i);
        float4 rv;
        rv.x = sm.Ot[nh + i + 0][c] * linvA[nh + i + 0] + xs.x;
        rv.y = sm.Ot[nh + i + 1][c] * linvA[nh + i + 1] + xs.y;
        rv.z = sm.Ot[nh + i + 2][c] * linvA[nh + i + 2] + xs.z;
        rv.w = sm.Ot[nh + i + 3][c] * linvA[nh + i + 3] + xs.w;
        *(float4*)(void*)(out + gb + i) = rv;
    }
}

// ---------------------------------------------------------------------------
extern "C" void kernel_launch(void* const* d_in, const int* in_sizes, int n_in,
                              void* d_out, int out_size, void* d_ws, size_t ws_size,
                              hipStream_t stream) {
    const float* x  = (const float*)d_in[0];
    const float* Wq = (const float*)d_in[1];
    const float* bq = (const float*)d_in[2];
    const float* Wk = (const float*)d_in[3];
    const float* bk = (const float*)d_in[4];
    const float* Wv = (const float*)d_in[5];
    const float* bv = (const float*)d_in[6];
    float* out = (float*)d_out;

    const long BCN = (long)B_ * C_ * N_;                  // 4,194,304
    unsigned short* kTs = (unsigned short*)d_ws;          // [b][n][o'] bf16 swizzled
    unsigned short* vS  = kTs + BCN;                      // [b][o][n'] bf16 swizzled

    // q lives in d_out [b][c][n] fp32 (pre-scaled): each attn block reads only
    // its own query columns and overwrites exactly those columns at the end.
    qkv_mfma<<<512, 256, 0, stream>>>(x, Wq, bq, Wk, bk, Wv, bv, out, kTs, vS);
    attn_mfma<<<B_ * (N_ / 64), 512, 0, stream>>>(out, kTs, vS, x, out);
}

// Round 8
// 190.929 us; speedup vs baseline: 1.3603x; 1.2235x over previous
//
#include <hip/hip_runtime.h>

#define B_ 8
#define C_ 128
#define N_ 4096
#define SCALE 0.08838834764831845f   // 1/sqrt(128)

typedef __attribute__((ext_vector_type(8))) short short8;   // 8 bf16
typedef __attribute__((ext_vector_type(4))) short short4v;  // 4 bf16
typedef __attribute__((ext_vector_type(4))) float f32x4;    // MFMA C/D

__device__ inline unsigned short f2b(float f) {            // RNE bf16 round
    unsigned int x = __float_as_uint(f);
    return (unsigned short)((x + 0x7FFFu + ((x >> 16) & 1u)) >> 16);
}

// async global->LDS, 16B per lane (m97 staging path).
__device__ inline void gld_lds16(const void* g, void* l) {
    __builtin_amdgcn_global_load_lds(
        (const __attribute__((address_space(1))) unsigned int*)g,
        (__attribute__((address_space(3))) unsigned int*)l, 16, 0, 0);
}

// ---------------------------------------------------------------------------
// MFMA QKV projection — EXACT R0 monolithic kernel (proven ~74-77 us across
// R0/R5 benches; every structural variant — pass-split, o-halved — regressed).
//  - pass order q -> v -> k, W A-frags of the NEXT pass prefetched before the
//    current pass's 32 MFMAs.
//  - q and v store DIRECTLY from C/D regs; only k keeps the Obuf epilogue.
// kTs bf16 [b][n][o'] o-blocks ^ (n&15) — UNPERMUTED (perm5 experiment
// R6/R7 failed deterministically; layout model for the swapped-operand path
// is unresolved — do not reintroduce without an on-device layout probe).
// vS bf16 [b][o][n'] 32-key windows, block' ^= (o>>1)&3. XCD map b = bid&7.
// mfma_f32_16x16x32_bf16: A[m=l15][k=quad*8+j]; B[k][n=l15];
// C/D row=quad*4+r, col=l15 (R6-R11 prior session, end-to-end validated).
// ---------------------------------------------------------------------------
__global__ __launch_bounds__(256) void qkv_mfma(
    const float* __restrict__ x,
    const float* __restrict__ Wq, const float* __restrict__ bq,
    const float* __restrict__ Wk, const float* __restrict__ bk,
    const float* __restrict__ Wv, const float* __restrict__ bv,
    float* __restrict__ q, unsigned short* __restrict__ kTs,
    unsigned short* __restrict__ vS)
{
    __shared__ __align__(16) short Xs[64 * 128];    // 16 KB bf16 X^T, swizzled
    __shared__ __align__(16) float Obuf[64 * 132];  // 33.8 KB k-epilogue

    const int t    = threadIdx.x;
    const int w    = t >> 6;
    const int lane = t & 63;
    const int l15  = lane & 15;
    const int quad = lane >> 4;

    const int b  = blockIdx.x & 7;               // XCD-pinned batch
    const int n0 = (blockIdx.x >> 3) * 64;
    const long base = (long)b * C_ * N_;

    auto load_af = [&](const float* __restrict__ W, short8 (&af)[2][4]) {
        #pragma unroll
        for (int ot = 0; ot < 2; ++ot) {
            const int o = 32 * w + 16 * ot + l15;
            #pragma unroll
            for (int ks = 0; ks < 4; ++ks) {
                const float4 a0 = *(const float4*)(const void*)(W + o * C_ + ks * 32 + quad * 8);
                const float4 a1 = *(const float4*)(const void*)(W + o * C_ + ks * 32 + quad * 8 + 4);
                short8 f;
                f[0] = (short)f2b(a0.x); f[1] = (short)f2b(a0.y);
                f[2] = (short)f2b(a0.z); f[3] = (short)f2b(a0.w);
                f[4] = (short)f2b(a1.x); f[5] = (short)f2b(a1.y);
                f[6] = (short)f2b(a1.z); f[7] = (short)f2b(a1.w);
                af[ot][ks] = f;
            }
        }
    };

    auto mfma_pass = [&](const short8 (&af)[2][4], f32x4 (&acc)[2][4]) {
        #pragma unroll
        for (int ot = 0; ot < 2; ++ot)
            #pragma unroll
            for (int nt = 0; nt < 4; ++nt)
                acc[ot][nt] = (f32x4){0.f, 0.f, 0.f, 0.f};
        #pragma unroll
        for (int nt = 0; nt < 4; ++nt) {
            const int n = nt * 16 + l15;
            short8 bx[4];
            #pragma unroll
            for (int ks = 0; ks < 4; ++ks)
                bx[ks] = *(const short8*)(const void*)(Xs + n * 128 + (((ks * 4 + quad) ^ l15) << 3));
            #pragma unroll
            for (int ot = 0; ot < 2; ++ot)
                #pragma unroll
                for (int ks = 0; ks < 4; ++ks)
                    acc[ot][nt] = __builtin_amdgcn_mfma_f32_16x16x32_bf16(af[ot][ks], bx[ks], acc[ot][nt], 0, 0, 0);
        }
    };

    // ---- W(q) A-frags first, then stage X^T tile ----
    short8 afA[2][4], afB[2][4];
    load_af(Wq, afA);

    #pragma unroll
    for (int it = 0; it < 8; ++it) {
        const int c  = (t >> 4) + it * 16;
        const int n4 = (t & 15) * 4;
        const float4 xv = *(const float4*)(const void*)(x + base + (long)c * N_ + n0 + n4);
        const int bc = c >> 3, cl = c & 7;
        Xs[(n4 + 0) * 128 + ((bc ^ ((n4 + 0) & 15)) << 3) + cl] = (short)f2b(xv.x);
        Xs[(n4 + 1) * 128 + ((bc ^ ((n4 + 1) & 15)) << 3) + cl] = (short)f2b(xv.y);
        Xs[(n4 + 2) * 128 + ((bc ^ ((n4 + 2) & 15)) << 3) + cl] = (short)f2b(xv.z);
        Xs[(n4 + 3) * 128 + ((bc ^ ((n4 + 3) & 15)) << 3) + cl] = (short)f2b(xv.w);
    }
    __syncthreads();

    { // ======== pass 1: q -> d_out fp32 [b][o][n], pre-scaled ========
        load_af(Wv, afB);                          // prefetch v weights
        f32x4 acc[2][4];
        mfma_pass(afA, acc);
        #pragma unroll
        for (int ot = 0; ot < 2; ++ot)
            #pragma unroll
            for (int r = 0; r < 4; ++r) {
                const int o = 32 * w + 16 * ot + quad * 4 + r;
                const float bb = bq[o];
                #pragma unroll
                for (int nt = 0; nt < 4; ++nt)
                    q[base + (long)o * N_ + n0 + nt * 16 + l15] = (acc[ot][nt][r] + bb) * SCALE;
            }
    }

    { // ======== pass 2: v -> vS bf16, direct swizzled store ========
        load_af(Wk, afA);                          // prefetch k weights
        f32x4 acc[2][4];
        mfma_pass(afB, acc);
        #pragma unroll
        for (int ot = 0; ot < 2; ++ot)
            #pragma unroll
            for (int r = 0; r < 4; ++r) {
                const int o = 32 * w + 16 * ot + quad * 4 + r;
                const float bb = bv[o];
                const int sw = ((o >> 1) & 3) << 3;
                #pragma unroll
                for (int nt = 0; nt < 4; ++nt) {
                    const int n = nt * 16 + l15;
                    const int ns = (n & 32) | ((((n >> 3) & 3) << 3) ^ sw) | (n & 7);
                    vS[base + (long)o * N_ + n0 + ns] = f2b(acc[ot][nt][r] + bb);
                }
            }
    }

    { // ======== pass 3: k -> kTs bf16 [b][n][o'] via Obuf (stride 132) ========
        f32x4 acc[2][4];
        mfma_pass(afA, acc);
        #pragma unroll
        for (int ot = 0; ot < 2; ++ot)
            #pragma unroll
            for (int r = 0; r < 4; ++r) {
                const int o = 32 * w + 16 * ot + quad * 4 + r;
                const float bb = bk[o];
                #pragma unroll
                for (int nt = 0; nt < 4; ++nt) {
                    const int n = nt * 16 + l15;
                    Obuf[n * 132 + (((o >> 3) ^ l15) << 3) + (o & 7)] = acc[ot][nt][r] + bb;
                }
            }
        __syncthreads();
        const int n = t >> 2, oh = (t & 3) * 32;
        #pragma unroll
        for (int i = 0; i < 32; i += 4) {
            const float4 kv = *(const float4*)(const void*)(Obuf + n * 132 + oh + i);
            short4v s;
            s[0] = (short)f2b(kv.x); s[1] = (short)f2b(kv.y);
            s[2] = (short)f2b(kv.z); s[3] = (short)f2b(kv.w);
            *(short4v*)(void*)(kTs + base + (long)(n0 + n) * C_ + oh + i) = s;
        }
    }
}

// ---------------------------------------------------------------------------
// MFMA flash attention + residual — EXACT R3 kernel (measured 107.5 us,
// passed). K frags global->reg (kTs swizzle inverts per-lane since
// key&15 == l15); single barrier/iter (vmcnt(4)+lgkmcnt(0)+s_barrier); P
// iter-parity double buffer; V double-buffered via gld_lds16; b128 V reads
// at block quad ^ (l15>>1)&3; __expf; setprio around MFMA clusters.
// Wave roles (w = g*4 + wq*2 + h): QK computes P[32q][16k(h)]; PV consumes
// full P[32q][32k] for channel-half h.
// ---------------------------------------------------------------------------
__global__ __launch_bounds__(512, 4) void attn_mfma(
    const float* qg,                  // aliases out (q written by qkv, fp32)
    const unsigned short* __restrict__ kTs,
    const unsigned short* __restrict__ vS,
    const float* __restrict__ xg,
    float* out)
{
    __shared__ union {
        struct {
            short V[2][2][4096];         // [buf][grp][128 ch x 32 keys] swizzled
            short Pb[2][2][2][32 * 40];  // [iter-parity][grp][wq] 32q x 32k
        } s;
        float Ot[64 * 130];              // epilogue merge buffer
    } sm;
    __shared__ float Ls[2][2][32];       // [g][wq][row32] row-sums
    __shared__ float linvA[64];

    const int t    = threadIdx.x;
    const int w    = t >> 6;          // 0..7
    const int g    = w >> 2;          // key-group (2048-key half)
    const int wq   = (w >> 1) & 1;    // 32-query subtile
    const int h    = w & 1;           // QK: key-half; PV: channel-half
    const int sub  = w & 3;           // staging sub-tile
    const int lane = t & 63;
    const int l15  = lane & 15;
    const int quad = lane >> 4;

    const int b  = blockIdx.x & 7;               // XCD-pinned batch
    const int n0 = (blockIdx.x >> 3) * 64;
    const long base = (long)b * C_ * N_;

    // ---- Q A-frags: 32 queries per wave (2 x 16q subtiles) ----
    const int query0 = n0 + 32 * wq;
    short8 qf[2][4];
    #pragma unroll
    for (int qh = 0; qh < 2; ++qh)
        #pragma unroll
        for (int ks = 0; ks < 4; ++ks) {
            short8 f;
            #pragma unroll
            for (int j = 0; j < 8; ++j) {
                const int c = ks * 32 + quad * 8 + j;
                f[j] = (short)f2b(qg[base + (long)c * N_ + query0 + qh * 16 + l15]);
            }
            qf[qh][ks] = f;
        }

    f32x4 acc[2][4];                  // [qh][ct]: 32q x 64c (channel-half h)
    #pragma unroll
    for (int qh = 0; qh < 2; ++qh)
        #pragma unroll
        for (int ct = 0; ct < 4; ++ct) acc[qh][ct] = (f32x4){0.f, 0.f, 0.f, 0.f};
    f32x4 accS[2];
    accS[0] = (f32x4){0.f, 0.f, 0.f, 0.f};
    accS[1] = (f32x4){0.f, 0.f, 0.f, 0.f};
    short8 ones;
    #pragma unroll
    for (int j = 0; j < 8; ++j) ones[j] = (short)0x3F80;   // bf16 1.0

    auto stageV = [&](int buf, int pair) {       // exactly 2 VMEM ops / lane
        const int mt = pair * 2 + g;
        char* lV = (char*)sm.s.V[buf][g];
        #pragma unroll
        for (int jj = 0; jj < 2; ++jj) {
            const int d  = sub * 2048 + jj * 1024;
            const int dv = d + lane * 16;
            const int c  = dv >> 6;
            gld_lds16((const char*)(vS + base + (long)c * N_ + mt * 32) + (dv & 63), lV + d);
        }
    };

    // ---- K direct global->reg: key = mt*32 + h*16 + l15, key&15 == l15 so
    // the baked-in kTs swizzle inverts with the same XOR as the LDS path ----
    const unsigned short* kp = kTs + base + (long)((g * 32 + h * 16 + l15) * C_);
    int ko[4];
    #pragma unroll
    for (int ks = 0; ks < 4; ++ks) ko[ks] = (((ks * 4 + quad) ^ l15) << 3);
    short8 kf[4];

    stageV(0, 0);
    #pragma unroll
    for (int ks = 0; ks < 4; ++ks) kf[ks] = *(const short8*)(const void*)(kp + ko[ks]);
    kp += 64 * C_;

    for (int i = 0; i < 64; ++i) {
        // ---- QK phase (registers only): P[32q][16k(h)] ----
        f32x4 sc[2];
        sc[0] = (f32x4){0.f, 0.f, 0.f, 0.f};
        sc[1] = (f32x4){0.f, 0.f, 0.f, 0.f};
        __builtin_amdgcn_s_setprio(1);
        #pragma unroll
        for (int qh = 0; qh < 2; ++qh)
            #pragma unroll
            for (int ks = 0; ks < 4; ++ks)
                sc[qh] = __builtin_amdgcn_mfma_f32_16x16x32_bf16(qf[qh][ks], kf[ks], sc[qh], 0, 0, 0);
        __builtin_amdgcn_s_setprio(0);

        // ---- prefetch kf(i+1): regs free, ~full iteration in flight ----
        if (i < 63) {
            #pragma unroll
            for (int ks = 0; ks < 4; ++ks) kf[ks] = *(const short8*)(const void*)(kp + ko[ks]);
            kp += 64 * C_;
        }

        // ---- softmax numerator -> P (iter-parity double buffer) ----
        short* Pw = sm.s.Pb[i & 1][g][wq];
        #pragma unroll
        for (int qh = 0; qh < 2; ++qh)
            #pragma unroll
            for (int r = 0; r < 4; ++r)
                Pw[(qh * 16 + quad * 4 + r) * 40 + h * 16 + l15] = (short)f2b(__expf(sc[qh][r]));

        // ---- single sync point: V(i) staged (vmcnt: kf(i+1) stays in
        // flight), own P writes drained, then barrier ----
        if (i < 63) asm volatile("s_waitcnt vmcnt(4)" ::: "memory");
        else        asm volatile("s_waitcnt vmcnt(0)" ::: "memory");
        asm volatile("s_waitcnt lgkmcnt(0)" ::: "memory");
        __builtin_amdgcn_s_barrier();
        __builtin_amdgcn_sched_barrier(0);

        // ---- V(i+1) stage: earliest legal point (all PV(i-1) reads of this
        // buffer completed before anyone passed B(i)) ----
        if (i < 63) stageV((i + 1) & 1, i + 1);

        // ---- PV phase: channel-half h, full 32-key P ----
        const short* Vb = sm.s.V[i & 1][g];
        const short8 pf0 = *(const short8*)(const void*)(Pw + (l15) * 40 + quad * 8);
        const short8 pf1 = *(const short8*)(const void*)(Pw + (16 + l15) * 40 + quad * 8);
        __builtin_amdgcn_s_setprio(1);
        if (h == 0) {                          // row-sums once per (g,wq)
            accS[0] = __builtin_amdgcn_mfma_f32_16x16x32_bf16(pf0, ones, accS[0], 0, 0, 0);
            accS[1] = __builtin_amdgcn_mfma_f32_16x16x32_bf16(pf1, ones, accS[1], 0, 0, 0);
        }
        #pragma unroll
        for (int ct = 0; ct < 4; ++ct) {
            const int ch = h * 64 + ct * 16 + l15;
            const short8 vf = *(const short8*)(const void*)(Vb + ch * 32 + ((quad ^ ((l15 >> 1) & 3)) << 3));
            acc[0][ct] = __builtin_amdgcn_mfma_f32_16x16x32_bf16(pf0, vf, acc[0][ct], 0, 0, 0);
            acc[1][ct] = __builtin_amdgcn_mfma_f32_16x16x32_bf16(pf1, vf, acc[1][ct], 0, 0, 0);
        }
        __builtin_amdgcn_s_setprio(0);
    }

    // ---- merge epilogue: Ot = O_g0 + O_g1; l via Ls; normalize + residual ----
    if (h == 0 && l15 == 0) {
        #pragma unroll
        for (int qh = 0; qh < 2; ++qh)
            #pragma unroll
            for (int r = 0; r < 4; ++r)
                Ls[g][wq][qh * 16 + quad * 4 + r] = accS[qh][r];
    }
    __syncthreads();                  // all PV reads done before Ot overlays LDS
    if (g == 0) {
        #pragma unroll
        for (int qh = 0; qh < 2; ++qh)
            #pragma unroll
            for (int ct = 0; ct < 4; ++ct)
                #pragma unroll
                for (int r = 0; r < 4; ++r)
                    sm.Ot[(32 * wq + qh * 16 + quad * 4 + r) * 130 + h * 64 + ct * 16 + l15] = acc[qh][ct][r];
    }
    __syncthreads();
    if (g == 1) {
        #pragma unroll
        for (int qh = 0; qh < 2; ++qh)
            #pragma unroll
            for (int ct = 0; ct < 4; ++ct)
                #pragma unroll
                for (int r = 0; r < 4; ++r)
                    sm.Ot[(32 * wq + qh * 16 + quad * 4 + r) * 130 + h * 64 + ct * 16 + l15] += acc[qh][ct][r];
    } else if (h == 0 && l15 == 0) {
        #pragma unroll
        for (int qh = 0; qh < 2; ++qh)
            #pragma unroll
            for (int r = 0; r < 4; ++r) {
                const int r32 = qh * 16 + quad * 4 + r;
                linvA[32 * wq + r32] = 1.0f / fmaxf(Ls[0][wq][r32] + Ls[1][wq][r32], 1e-20f);
            }
    }
    __syncthreads();

    const int c  = t >> 2;
    const int nh = (t & 3) * 16;
    const long gb = base + (long)c * N_ + n0 + nh;
    #pragma unroll
    for (int i = 0; i < 16; i += 4) {
        const float4 xs = *(const float4*)(const void*)(xg + gb + i);
        float4 rv;
        rv.x = sm.Ot[(nh + i + 0) * 130 + c] * linvA[nh + i + 0] + xs.x;
        rv.y = sm.Ot[(nh + i + 1) * 130 + c] * linvA[nh + i + 1] + xs.y;
        rv.z = sm.Ot[(nh + i + 2) * 130 + c] * linvA[nh + i + 2] + xs.z;
        rv.w = sm.Ot[(nh + i + 3) * 130 + c] * linvA[nh + i + 3] + xs.w;
        *(float4*)(void*)(out + gb + i) = rv;
    }
}

// ---------------------------------------------------------------------------
extern "C" void kernel_launch(void* const* d_in, const int* in_sizes, int n_in,
                              void* d_out, int out_size, void* d_ws, size_t ws_size,
                              hipStream_t stream) {
    const float* x  = (const float*)d_in[0];
    const float* Wq = (const float*)d_in[1];
    const float* bq = (const float*)d_in[2];
    const float* Wk = (const float*)d_in[3];
    const float* bk = (const float*)d_in[4];
    const float* Wv = (const float*)d_in[5];
    const float* bv = (const float*)d_in[6];
    float* out = (float*)d_out;

    const long BCN = (long)B_ * C_ * N_;                  // 4,194,304
    unsigned short* kTs = (unsigned short*)d_ws;          // [b][n][o'] bf16 swizzled
    unsigned short* vS  = kTs + BCN;                      // [b][o][n'] bf16 swizzled

    // q lives in d_out [b][c][n] fp32 (pre-scaled): each attn block reads only
    // its own query columns and overwrites exactly those columns at the end.
    qkv_mfma<<<512, 256, 0, stream>>>(x, Wq, bq, Wk, bk, Wv, bv, out, kTs, vS);
    attn_mfma<<<B_ * (N_ / 64), 512, 0, stream>>>(out, kTs, vS, x, out);
}

// Round 9
// 190.498 us; speedup vs baseline: 1.3634x; 1.0023x over previous
//
#include <hip/hip_runtime.h>

#define B_ 8
#define C_ 128
#define N_ 4096
#define SCALE 0.08838834764831845f   // 1/sqrt(128)

typedef __attribute__((ext_vector_type(8))) short short8;   // 8 bf16
typedef __attribute__((ext_vector_type(4))) short short4v;  // 4 bf16
typedef __attribute__((ext_vector_type(4))) float f32x4;    // MFMA C/D

// RNE fp32->bf16, 1 VALU inst (v_cvt_pk_bf16_f32 with both srcs equal; low
// half taken). Pack order lo=src0 pinned by R5 (mfma16 PV passed with it).
__device__ inline unsigned short f2b(float f) {
    unsigned int u;
    asm("v_cvt_pk_bf16_f32 %0, %1, %2" : "=v"(u) : "v"(f), "v"(f));
    return (unsigned short)u;
}

// async global->LDS, 16B per lane (m97 staging path).
__device__ inline void gld_lds16(const void* g, void* l) {
    __builtin_amdgcn_global_load_lds(
        (const __attribute__((address_space(1))) unsigned int*)g,
        (__attribute__((address_space(3))) unsigned int*)l, 16, 0, 0);
}

// ---------------------------------------------------------------------------
// MFMA QKV projection — R0 monolithic structure (proven; every structural
// variant regressed -> the invariant bottleneck was the EPILOGUE: fragmented
// scalar stores + f2b VALU). R9 deltas:
//  - v-pass now goes through Obuf (fp32 [o][n], the proven k-pattern
//    transposed) and stores COALESCED 16B short8 with the ns swizzle applied
//    on the copy side (32 scattered 2B stores/wave -> 4x16B/thread).
//  - all fp32->bf16 via v_cvt_pk_bf16_f32 pairs (load_af: 192->16 inst).
// kTs bf16 [b][n][o'] o-blocks ^ (n&15). vS bf16 [b][o][n'] 32-key windows,
// block' ^= (o>>1)&3. XCD map b = bid&7.
// mfma_f32_16x16x32_bf16: A[m=l15][k=quad*8+j]; B[k][n=l15];
// C/D row=quad*4+r, col=l15 (end-to-end validated).
// ---------------------------------------------------------------------------
__global__ __launch_bounds__(256) void qkv_mfma(
    const float* __restrict__ x,
    const float* __restrict__ Wq, const float* __restrict__ bq,
    const float* __restrict__ Wk, const float* __restrict__ bk,
    const float* __restrict__ Wv, const float* __restrict__ bv,
    float* __restrict__ q, unsigned short* __restrict__ kTs,
    unsigned short* __restrict__ vS)
{
    __shared__ __align__(16) short Xs[64 * 128];    // 16 KB bf16 X^T, swizzled
    __shared__ __align__(16) float Obuf[64 * 132];  // 33.8 KB epilogue buffer

    const int t    = threadIdx.x;
    const int w    = t >> 6;
    const int lane = t & 63;
    const int l15  = lane & 15;
    const int quad = lane >> 4;

    const int b  = blockIdx.x & 7;               // XCD-pinned batch
    const int n0 = (blockIdx.x >> 3) * 64;
    const long base = (long)b * C_ * N_;

    auto load_af = [&](const float* __restrict__ W, short8 (&af)[2][4]) {
        #pragma unroll
        for (int ot = 0; ot < 2; ++ot) {
            const int o = 32 * w + 16 * ot + l15;
            #pragma unroll
            for (int ks = 0; ks < 4; ++ks) {
                const float4 a0 = *(const float4*)(const void*)(W + o * C_ + ks * 32 + quad * 8);
                const float4 a1 = *(const float4*)(const void*)(W + o * C_ + ks * 32 + quad * 8 + 4);
                union { unsigned int u[4]; short8 s; } pk;
                asm("v_cvt_pk_bf16_f32 %0, %1, %2" : "=v"(pk.u[0]) : "v"(a0.x), "v"(a0.y));
                asm("v_cvt_pk_bf16_f32 %0, %1, %2" : "=v"(pk.u[1]) : "v"(a0.z), "v"(a0.w));
                asm("v_cvt_pk_bf16_f32 %0, %1, %2" : "=v"(pk.u[2]) : "v"(a1.x), "v"(a1.y));
                asm("v_cvt_pk_bf16_f32 %0, %1, %2" : "=v"(pk.u[3]) : "v"(a1.z), "v"(a1.w));
                af[ot][ks] = pk.s;
            }
        }
    };

    auto mfma_pass = [&](const short8 (&af)[2][4], f32x4 (&acc)[2][4]) {
        #pragma unroll
        for (int ot = 0; ot < 2; ++ot)
            #pragma unroll
            for (int nt = 0; nt < 4; ++nt)
                acc[ot][nt] = (f32x4){0.f, 0.f, 0.f, 0.f};
        #pragma unroll
        for (int nt = 0; nt < 4; ++nt) {
            const int n = nt * 16 + l15;
            short8 bx[4];
            #pragma unroll
            for (int ks = 0; ks < 4; ++ks)
                bx[ks] = *(const short8*)(const void*)(Xs + n * 128 + (((ks * 4 + quad) ^ l15) << 3));
            #pragma unroll
            for (int ot = 0; ot < 2; ++ot)
                #pragma unroll
                for (int ks = 0; ks < 4; ++ks)
                    acc[ot][nt] = __builtin_amdgcn_mfma_f32_16x16x32_bf16(af[ot][ks], bx[ks], acc[ot][nt], 0, 0, 0);
        }
    };

    // ---- W(q) A-frags first, then stage X^T tile ----
    short8 afA[2][4], afB[2][4];
    load_af(Wq, afA);

    #pragma unroll
    for (int it = 0; it < 8; ++it) {
        const int c  = (t >> 4) + it * 16;
        const int n4 = (t & 15) * 4;
        const float4 xv = *(const float4*)(const void*)(x + base + (long)c * N_ + n0 + n4);
        const int bc = c >> 3, cl = c & 7;
        Xs[(n4 + 0) * 128 + ((bc ^ ((n4 + 0) & 15)) << 3) + cl] = (short)f2b(xv.x);
        Xs[(n4 + 1) * 128 + ((bc ^ ((n4 + 1) & 15)) << 3) + cl] = (short)f2b(xv.y);
        Xs[(n4 + 2) * 128 + ((bc ^ ((n4 + 2) & 15)) << 3) + cl] = (short)f2b(xv.z);
        Xs[(n4 + 3) * 128 + ((bc ^ ((n4 + 3) & 15)) << 3) + cl] = (short)f2b(xv.w);
    }
    __syncthreads();

    { // ======== pass 1: q -> d_out fp32 [b][o][n], pre-scaled ========
        load_af(Wv, afB);                          // prefetch v weights
        f32x4 acc[2][4];
        mfma_pass(afA, acc);
        #pragma unroll
        for (int ot = 0; ot < 2; ++ot)
            #pragma unroll
            for (int r = 0; r < 4; ++r) {
                const int o = 32 * w + 16 * ot + quad * 4 + r;
                const float bb = bq[o];
                #pragma unroll
                for (int nt = 0; nt < 4; ++nt)
                    q[base + (long)o * N_ + n0 + nt * 16 + l15] = (acc[ot][nt][r] + bb) * SCALE;
            }
    }

    { // ======== pass 2: v -> Obuf_v fp32 [o][n] -> coalesced bf16 stores ====
        load_af(Wk, afA);                          // prefetch k weights
        f32x4 acc[2][4];
        mfma_pass(afB, acc);
        #pragma unroll
        for (int ot = 0; ot < 2; ++ot)
            #pragma unroll
            for (int r = 0; r < 4; ++r) {
                const int o = 32 * w + 16 * ot + quad * 4 + r;
                const float bb = bv[o];
                #pragma unroll
                for (int nt = 0; nt < 4; ++nt)
                    Obuf[o * 66 + nt * 16 + l15] = acc[ot][nt][r] + bb;   // 2-way banks
            }
        __syncthreads();
        { // copy: t -> (o = t>>1, 32-col half = t&1); 4 swizzled short8 stores
            const int o = t >> 1, half = (t & 1) * 32;
            const int sw = (o >> 1) & 3;
            #pragma unroll
            for (int bs = 0; bs < 4; ++bs) {
                const float4 v0 = *(const float4*)(const void*)(Obuf + o * 66 + half + bs * 8);
                const float4 v1 = *(const float4*)(const void*)(Obuf + o * 66 + half + bs * 8 + 4);
                union { unsigned int u[4]; short8 s; } pk;
                asm("v_cvt_pk_bf16_f32 %0, %1, %2" : "=v"(pk.u[0]) : "v"(v0.x), "v"(v0.y));
                asm("v_cvt_pk_bf16_f32 %0, %1, %2" : "=v"(pk.u[1]) : "v"(v0.z), "v"(v0.w));
                asm("v_cvt_pk_bf16_f32 %0, %1, %2" : "=v"(pk.u[2]) : "v"(v1.x), "v"(v1.y));
                asm("v_cvt_pk_bf16_f32 %0, %1, %2" : "=v"(pk.u[3]) : "v"(v1.z), "v"(v1.w));
                *(short8*)(void*)(vS + base + (long)o * N_ + n0 + half + ((bs ^ sw) << 3)) = pk.s;
            }
        }
        __syncthreads();                           // Obuf free for k-pass
    }

    { // ======== pass 3: k -> kTs bf16 [b][n][o'] via Obuf (stride 132) ========
        f32x4 acc[2][4];
        mfma_pass(afA, acc);
        #pragma unroll
        for (int ot = 0; ot < 2; ++ot)
            #pragma unroll
            for (int r = 0; r < 4; ++r) {
                const int o = 32 * w + 16 * ot + quad * 4 + r;
                const float bb = bk[o];
                #pragma unroll
                for (int nt = 0; nt < 4; ++nt) {
                    const int n = nt * 16 + l15;
                    Obuf[n * 132 + (((o >> 3) ^ l15) << 3) + (o & 7)] = acc[ot][nt][r] + bb;
                }
            }
        __syncthreads();
        const int n = t >> 2, oh = (t & 3) * 32;
        #pragma unroll
        for (int i = 0; i < 32; i += 8) {
            const float4 k0 = *(const float4*)(const void*)(Obuf + n * 132 + oh + i);
            const float4 k1 = *(const float4*)(const void*)(Obuf + n * 132 + oh + i + 4);
            union { unsigned int u[4]; short8 s; } pk;
            asm("v_cvt_pk_bf16_f32 %0, %1, %2" : "=v"(pk.u[0]) : "v"(k0.x), "v"(k0.y));
            asm("v_cvt_pk_bf16_f32 %0, %1, %2" : "=v"(pk.u[1]) : "v"(k0.z), "v"(k0.w));
            asm("v_cvt_pk_bf16_f32 %0, %1, %2" : "=v"(pk.u[2]) : "v"(k1.x), "v"(k1.y));
            asm("v_cvt_pk_bf16_f32 %0, %1, %2" : "=v"(pk.u[3]) : "v"(k1.z), "v"(k1.w));
            *(short8*)(void*)(kTs + base + (long)(n0 + n) * C_ + oh + i) = pk.s;
        }
    }
}

// ---------------------------------------------------------------------------
// MFMA flash attention + residual — R3/R8 kernel (measured 107.5-109.6 us,
// passed twice). Only R9 delta: P-write f2b is now the 1-inst cvt_pk form
// (identical RNE bits). Everything else byte-identical.
// ---------------------------------------------------------------------------
__global__ __launch_bounds__(512, 4) void attn_mfma(
    const float* qg,                  // aliases out (q written by qkv, fp32)
    const unsigned short* __restrict__ kTs,
    const unsigned short* __restrict__ vS,
    const float* __restrict__ xg,
    float* out)
{
    __shared__ union {
        struct {
            short V[2][2][4096];         // [buf][grp][128 ch x 32 keys] swizzled
            short Pb[2][2][2][32 * 40];  // [iter-parity][grp][wq] 32q x 32k
        } s;
        float Ot[64 * 130];              // epilogue merge buffer
    } sm;
    __shared__ float Ls[2][2][32];       // [g][wq][row32] row-sums
    __shared__ float linvA[64];

    const int t    = threadIdx.x;
    const int w    = t >> 6;          // 0..7
    const int g    = w >> 2;          // key-group (2048-key half)
    const int wq   = (w >> 1) & 1;    // 32-query subtile
    const int h    = w & 1;           // QK: key-half; PV: channel-half
    const int sub  = w & 3;           // staging sub-tile
    const int lane = t & 63;
    const int l15  = lane & 15;
    const int quad = lane >> 4;

    const int b  = blockIdx.x & 7;               // XCD-pinned batch
    const int n0 = (blockIdx.x >> 3) * 64;
    const long base = (long)b * C_ * N_;

    // ---- Q A-frags: 32 queries per wave (2 x 16q subtiles) ----
    const int query0 = n0 + 32 * wq;
    short8 qf[2][4];
    #pragma unroll
    for (int qh = 0; qh < 2; ++qh)
        #pragma unroll
        for (int ks = 0; ks < 4; ++ks) {
            short8 f;
            #pragma unroll
            for (int j = 0; j < 8; ++j) {
                const int c = ks * 32 + quad * 8 + j;
                f[j] = (short)f2b(qg[base + (long)c * N_ + query0 + qh * 16 + l15]);
            }
            qf[qh][ks] = f;
        }

    f32x4 acc[2][4];                  // [qh][ct]: 32q x 64c (channel-half h)
    #pragma unroll
    for (int qh = 0; qh < 2; ++qh)
        #pragma unroll
        for (int ct = 0; ct < 4; ++ct) acc[qh][ct] = (f32x4){0.f, 0.f, 0.f, 0.f};
    f32x4 accS[2];
    accS[0] = (f32x4){0.f, 0.f, 0.f, 0.f};
    accS[1] = (f32x4){0.f, 0.f, 0.f, 0.f};
    short8 ones;
    #pragma unroll
    for (int j = 0; j < 8; ++j) ones[j] = (short)0x3F80;   // bf16 1.0

    auto stageV = [&](int buf, int pair) {       // exactly 2 VMEM ops / lane
        const int mt = pair * 2 + g;
        char* lV = (char*)sm.s.V[buf][g];
        #pragma unroll
        for (int jj = 0; jj < 2; ++jj) {
            const int d  = sub * 2048 + jj * 1024;
            const int dv = d + lane * 16;
            const int c  = dv >> 6;
            gld_lds16((const char*)(vS + base + (long)c * N_ + mt * 32) + (dv & 63), lV + d);
        }
    };

    // ---- K direct global->reg: key = mt*32 + h*16 + l15, key&15 == l15 so
    // the baked-in kTs swizzle inverts with the same XOR as the LDS path ----
    const unsigned short* kp = kTs + base + (long)((g * 32 + h * 16 + l15) * C_);
    int ko[4];
    #pragma unroll
    for (int ks = 0; ks < 4; ++ks) ko[ks] = (((ks * 4 + quad) ^ l15) << 3);
    short8 kf[4];

    stageV(0, 0);
    #pragma unroll
    for (int ks = 0; ks < 4; ++ks) kf[ks] = *(const short8*)(const void*)(kp + ko[ks]);
    kp += 64 * C_;

    for (int i = 0; i < 64; ++i) {
        // ---- QK phase (registers only): P[32q][16k(h)] ----
        f32x4 sc[2];
        sc[0] = (f32x4){0.f, 0.f, 0.f, 0.f};
        sc[1] = (f32x4){0.f, 0.f, 0.f, 0.f};
        __builtin_amdgcn_s_setprio(1);
        #pragma unroll
        for (int qh = 0; qh < 2; ++qh)
            #pragma unroll
            for (int ks = 0; ks < 4; ++ks)
                sc[qh] = __builtin_amdgcn_mfma_f32_16x16x32_bf16(qf[qh][ks], kf[ks], sc[qh], 0, 0, 0);
        __builtin_amdgcn_s_setprio(0);

        // ---- prefetch kf(i+1): regs free, ~full iteration in flight ----
        if (i < 63) {
            #pragma unroll
            for (int ks = 0; ks < 4; ++ks) kf[ks] = *(const short8*)(const void*)(kp + ko[ks]);
            kp += 64 * C_;
        }

        // ---- softmax numerator -> P (iter-parity double buffer) ----
        short* Pw = sm.s.Pb[i & 1][g][wq];
        #pragma unroll
        for (int qh = 0; qh < 2; ++qh)
            #pragma unroll
            for (int r = 0; r < 4; ++r)
                Pw[(qh * 16 + quad * 4 + r) * 40 + h * 16 + l15] = (short)f2b(__expf(sc[qh][r]));

        // ---- single sync point: V(i) staged (vmcnt: kf(i+1) stays in
        // flight), own P writes drained, then barrier ----
        if (i < 63) asm volatile("s_waitcnt vmcnt(4)" ::: "memory");
        else        asm volatile("s_waitcnt vmcnt(0)" ::: "memory");
        asm volatile("s_waitcnt lgkmcnt(0)" ::: "memory");
        __builtin_amdgcn_s_barrier();
        __builtin_amdgcn_sched_barrier(0);

        // ---- V(i+1) stage: earliest legal point (all PV(i-1) reads of this
        // buffer completed before anyone passed B(i)) ----
        if (i < 63) stageV((i + 1) & 1, i + 1);

        // ---- PV phase: channel-half h, full 32-key P ----
        const short* Vb = sm.s.V[i & 1][g];
        const short8 pf0 = *(const short8*)(const void*)(Pw + (l15) * 40 + quad * 8);
        const short8 pf1 = *(const short8*)(const void*)(Pw + (16 + l15) * 40 + quad * 8);
        __builtin_amdgcn_s_setprio(1);
        if (h == 0) {                          // row-sums once per (g,wq)
            accS[0] = __builtin_amdgcn_mfma_f32_16x16x32_bf16(pf0, ones, accS[0], 0, 0, 0);
            accS[1] = __builtin_amdgcn_mfma_f32_16x16x32_bf16(pf1, ones, accS[1], 0, 0, 0);
        }
        #pragma unroll
        for (int ct = 0; ct < 4; ++ct) {
            const int ch = h * 64 + ct * 16 + l15;
            const short8 vf = *(const short8*)(const void*)(Vb + ch * 32 + ((quad ^ ((l15 >> 1) & 3)) << 3));
            acc[0][ct] = __builtin_amdgcn_mfma_f32_16x16x32_bf16(pf0, vf, acc[0][ct], 0, 0, 0);
            acc[1][ct] = __builtin_amdgcn_mfma_f32_16x16x32_bf16(pf1, vf, acc[1][ct], 0, 0, 0);
        }
        __builtin_amdgcn_s_setprio(0);
    }

    // ---- merge epilogue: Ot = O_g0 + O_g1; l via Ls; normalize + residual ----
    if (h == 0 && l15 == 0) {
        #pragma unroll
        for (int qh = 0; qh < 2; ++qh)
            #pragma unroll
            for (int r = 0; r < 4; ++r)
                Ls[g][wq][qh * 16 + quad * 4 + r] = accS[qh][r];
    }
    __syncthreads();                  // all PV reads done before Ot overlays LDS
    if (g == 0) {
        #pragma unroll
        for (int qh = 0; qh < 2; ++qh)
            #pragma unroll
            for (int ct = 0; ct < 4; ++ct)
                #pragma unroll
                for (int r = 0; r < 4; ++r)
                    sm.Ot[(32 * wq + qh * 16 + quad * 4 + r) * 130 + h * 64 + ct * 16 + l15] = acc[qh][ct][r];
    }
    __syncthreads();
    if (g == 1) {
        #pragma unroll
        for (int qh = 0; qh < 2; ++qh)
            #pragma unroll
            for (int ct = 0; ct < 4; ++ct)
                #pragma unroll
                for (int r = 0; r < 4; ++r)
                    sm.Ot[(32 * wq + qh * 16 + quad * 4 + r) * 130 + h * 64 + ct * 16 + l15] += acc[qh][ct][r];
    } else if (h == 0 && l15 == 0) {
        #pragma unroll
        for (int qh = 0; qh < 2; ++qh)
            #pragma unroll
            for (int r = 0; r < 4; ++r) {
                const int r32 = qh * 16 + quad * 4 + r;
                linvA[32 * wq + r32] = 1.0f / fmaxf(Ls[0][wq][r32] + Ls[1][wq][r32], 1e-20f);
            }
    }
    __syncthreads();

    const int c  = t >> 2;
    const int nh = (t & 3) * 16;
    const long gb = base + (long)c * N_ + n0 + nh;
    #pragma unroll
    for (int i = 0; i < 16; i += 4) {
        const float4 xs = *(const float4*)(const void*)(xg + gb + i);
        float4 rv;
        rv.x = sm.Ot[(nh + i + 0) * 130 + c] * linvA[nh + i + 0] + xs.x;
        rv.y = sm.Ot[(nh + i + 1) * 130 + c] * linvA[nh + i + 1] + xs.y;
        rv.z = sm.Ot[(nh + i + 2) * 130 + c] * linvA[nh + i + 2] + xs.z;
        rv.w = sm.Ot[(nh + i + 3) * 130 + c] * linvA[nh + i + 3] + xs.w;
        *(float4*)(void*)(out + gb + i) = rv;
    }
}

// ---------------------------------------------------------------------------
extern "C" void kernel_launch(void* const* d_in, const int* in_sizes, int n_in,
                              void* d_out, int out_size, void* d_ws, size_t ws_size,
                              hipStream_t stream) {
    const float* x  = (const float*)d_in[0];
    const float* Wq = (const float*)d_in[1];
    const float* bq = (const float*)d_in[2];
    const float* Wk = (const float*)d_in[3];
    const float* bk = (const float*)d_in[4];
    const float* Wv = (const float*)d_in[5];
    const float* bv = (const float*)d_in[6];
    float* out = (float*)d_out;

    const long BCN = (long)B_ * C_ * N_;                  // 4,194,304
    unsigned short* kTs = (unsigned short*)d_ws;          // [b][n][o'] bf16 swizzled
    unsigned short* vS  = kTs + BCN;                      // [b][o][n'] bf16 swizzled

    // q lives in d_out [b][c][n] fp32 (pre-scaled): each attn block reads only
    // its own query columns and overwrites exactly those columns at the end.
    qkv_mfma<<<512, 256, 0, stream>>>(x, Wq, bq, Wk, bk, Wv, bv, out, kTs, vS);
    attn_mfma<<<B_ * (N_ / 64), 512, 0, stream>>>(out, kTs, vS, x, out);
}

// Round 10
// 180.889 us; speedup vs baseline: 1.4358x; 1.0531x over previous
//
#include <hip/hip_runtime.h>

#define B_ 8
#define C_ 128
#define N_ 4096
#define SCALE 0.08838834764831845f   // 1/sqrt(128)

typedef __attribute__((ext_vector_type(8))) short short8;   // 8 bf16
typedef __attribute__((ext_vector_type(4))) short short4v;  // 4 bf16
typedef __attribute__((ext_vector_type(4))) float f32x4;    // MFMA C/D

// RNE fp32->bf16, 1 VALU inst (v_cvt_pk_bf16_f32, low half).
__device__ inline unsigned short f2b(float f) {
    unsigned int u;
    asm("v_cvt_pk_bf16_f32 %0, %1, %2" : "=v"(u) : "v"(f), "v"(f));
    return (unsigned short)u;
}

// async global->LDS, 16B per lane (m97 staging path).
__device__ inline void gld_lds16(const void* g, void* l) {
    __builtin_amdgcn_global_load_lds(
        (const __attribute__((address_space(1))) unsigned int*)g,
        (__attribute__((address_space(3))) unsigned int*)l, 16, 0, 0);
}

// ---------------------------------------------------------------------------
// KV projection (R10): the proven R0/R8 monolithic qkv MINUS the q-pass —
// q is now computed inside attn (per-block 64-query tile), removing a third
// of the serial chain and the 33.6 MB q global round-trip.
//  - Wv A-frags first; Wk prefetched during the v-pass MFMAs.
//  - v: direct swizzled scalar stores (R8-proven; R9's LDS-coalesced variant
//    regressed +4 us). k: Obuf (stride 132) + cvt_pk short8 copy (R9 form).
// kTs bf16 [b][n][o'] o-blocks ^ (n&15). vS bf16 [b][o][n'] 32-key windows,
// block' ^= (o>>1)&3. XCD map b = bid&7.
// mfma_f32_16x16x32_bf16: A[m=l15][k=quad*8+j]; B[k][n=l15];
// C/D row=quad*4+r, col=l15 (end-to-end validated).
// ---------------------------------------------------------------------------
__global__ __launch_bounds__(256) void kv_mfma(
    const float* __restrict__ x,
    const float* __restrict__ Wk, const float* __restrict__ bk,
    const float* __restrict__ Wv, const float* __restrict__ bv,
    unsigned short* __restrict__ kTs, unsigned short* __restrict__ vS)
{
    __shared__ __align__(16) short Xs[64 * 128];    // 16 KB bf16 X^T, swizzled
    __shared__ __align__(16) float Obuf[64 * 132];  // 33.8 KB k-epilogue

    const int t    = threadIdx.x;
    const int w    = t >> 6;
    const int lane = t & 63;
    const int l15  = lane & 15;
    const int quad = lane >> 4;

    const int b  = blockIdx.x & 7;               // XCD-pinned batch
    const int n0 = (blockIdx.x >> 3) * 64;
    const long base = (long)b * C_ * N_;

    auto load_af = [&](const float* __restrict__ W, short8 (&af)[2][4]) {
        #pragma unroll
        for (int ot = 0; ot < 2; ++ot) {
            const int o = 32 * w + 16 * ot + l15;
            #pragma unroll
            for (int ks = 0; ks < 4; ++ks) {
                const float4 a0 = *(const float4*)(const void*)(W + o * C_ + ks * 32 + quad * 8);
                const float4 a1 = *(const float4*)(const void*)(W + o * C_ + ks * 32 + quad * 8 + 4);
                union { unsigned int u[4]; short8 s; } pk;
                asm("v_cvt_pk_bf16_f32 %0, %1, %2" : "=v"(pk.u[0]) : "v"(a0.x), "v"(a0.y));
                asm("v_cvt_pk_bf16_f32 %0, %1, %2" : "=v"(pk.u[1]) : "v"(a0.z), "v"(a0.w));
                asm("v_cvt_pk_bf16_f32 %0, %1, %2" : "=v"(pk.u[2]) : "v"(a1.x), "v"(a1.y));
                asm("v_cvt_pk_bf16_f32 %0, %1, %2" : "=v"(pk.u[3]) : "v"(a1.z), "v"(a1.w));
                af[ot][ks] = pk.s;
            }
        }
    };

    auto mfma_pass = [&](const short8 (&af)[2][4], f32x4 (&acc)[2][4]) {
        #pragma unroll
        for (int ot = 0; ot < 2; ++ot)
            #pragma unroll
            for (int nt = 0; nt < 4; ++nt)
                acc[ot][nt] = (f32x4){0.f, 0.f, 0.f, 0.f};
        #pragma unroll
        for (int nt = 0; nt < 4; ++nt) {
            const int n = nt * 16 + l15;
            short8 bx[4];
            #pragma unroll
            for (int ks = 0; ks < 4; ++ks)
                bx[ks] = *(const short8*)(const void*)(Xs + n * 128 + (((ks * 4 + quad) ^ l15) << 3));
            #pragma unroll
            for (int ot = 0; ot < 2; ++ot)
                #pragma unroll
                for (int ks = 0; ks < 4; ++ks)
                    acc[ot][nt] = __builtin_amdgcn_mfma_f32_16x16x32_bf16(af[ot][ks], bx[ks], acc[ot][nt], 0, 0, 0);
        }
    };

    // ---- W(v) A-frags first, then stage X^T tile ----
    short8 afA[2][4], afB[2][4];
    load_af(Wv, afA);

    #pragma unroll
    for (int it = 0; it < 8; ++it) {
        const int c  = (t >> 4) + it * 16;
        const int n4 = (t & 15) * 4;
        const float4 xv = *(const float4*)(const void*)(x + base + (long)c * N_ + n0 + n4);
        const int bc = c >> 3, cl = c & 7;
        Xs[(n4 + 0) * 128 + ((bc ^ ((n4 + 0) & 15)) << 3) + cl] = (short)f2b(xv.x);
        Xs[(n4 + 1) * 128 + ((bc ^ ((n4 + 1) & 15)) << 3) + cl] = (short)f2b(xv.y);
        Xs[(n4 + 2) * 128 + ((bc ^ ((n4 + 2) & 15)) << 3) + cl] = (short)f2b(xv.z);
        Xs[(n4 + 3) * 128 + ((bc ^ ((n4 + 3) & 15)) << 3) + cl] = (short)f2b(xv.w);
    }
    __syncthreads();

    { // ======== pass 1: v -> vS bf16, direct swizzled store (R8 form) ========
        load_af(Wk, afB);                          // prefetch k weights
        f32x4 acc[2][4];
        mfma_pass(afA, acc);
        #pragma unroll
        for (int ot = 0; ot < 2; ++ot)
            #pragma unroll
            for (int r = 0; r < 4; ++r) {
                const int o = 32 * w + 16 * ot + quad * 4 + r;
                const float bb = bv[o];
                const int sw = ((o >> 1) & 3) << 3;
                #pragma unroll
                for (int nt = 0; nt < 4; ++nt) {
                    const int n = nt * 16 + l15;
                    const int ns = (n & 32) | ((((n >> 3) & 3) << 3) ^ sw) | (n & 7);
                    vS[base + (long)o * N_ + n0 + ns] = f2b(acc[ot][nt][r] + bb);
                }
            }
    }

    { // ======== pass 2: k -> kTs bf16 [b][n][o'] via Obuf (stride 132) ========
        f32x4 acc[2][4];
        mfma_pass(afB, acc);
        #pragma unroll
        for (int ot = 0; ot < 2; ++ot)
            #pragma unroll
            for (int r = 0; r < 4; ++r) {
                const int o = 32 * w + 16 * ot + quad * 4 + r;
                const float bb = bk[o];
                #pragma unroll
                for (int nt = 0; nt < 4; ++nt) {
                    const int n = nt * 16 + l15;
                    Obuf[n * 132 + (((o >> 3) ^ l15) << 3) + (o & 7)] = acc[ot][nt][r] + bb;
                }
            }
        __syncthreads();
        const int n = t >> 2, oh = (t & 3) * 32;
        #pragma unroll
        for (int i = 0; i < 32; i += 8) {
            const float4 k0 = *(const float4*)(const void*)(Obuf + n * 132 + oh + i);
            const float4 k1 = *(const float4*)(const void*)(Obuf + n * 132 + oh + i + 4);
            union { unsigned int u[4]; short8 s; } pk;
            asm("v_cvt_pk_bf16_f32 %0, %1, %2" : "=v"(pk.u[0]) : "v"(k0.x), "v"(k0.y));
            asm("v_cvt_pk_bf16_f32 %0, %1, %2" : "=v"(pk.u[1]) : "v"(k0.z), "v"(k0.w));
            asm("v_cvt_pk_bf16_f32 %0, %1, %2" : "=v"(pk.u[2]) : "v"(k1.x), "v"(k1.y));
            asm("v_cvt_pk_bf16_f32 %0, %1, %2" : "=v"(pk.u[3]) : "v"(k1.z), "v"(k1.w));
            *(short8*)(void*)(kTs + base + (long)(n0 + n) * C_ + oh + i) = pk.s;
        }
    }
}

// ---------------------------------------------------------------------------
// MFMA flash attention + residual, R10: Q computed IN-BLOCK (preamble),
// main loop byte-identical to R9 (105.2 us proven).
// Preamble: stage X^T (verbatim staging -> bit-identical Xs), per-wave Wq
// A-frags (verbatim load_af pattern, o=16w+l15), 16 MFMA, write
// (acc+bq)*SCALE bf16 into Qs in Xs-format, read qf as b128 (verbatim bx
// pattern). Q frag bits are IDENTICAL to the old global-q path.
// LDS overlay: Xst=V[0] region, Qs=V[1] region. Safe because (a) all Xst
// reads complete before the post-Q sync, and stageV(0,0) is issued after it;
// (b) each wave's qf ds_reads complete (lgkmcnt) before its QK(0), which
// precedes the i=0 barrier, which precedes any stageV(1,1) write.
// ---------------------------------------------------------------------------
__global__ __launch_bounds__(512, 4) void attn_mfma(
    const float* __restrict__ Wq, const float* __restrict__ bq,
    const unsigned short* __restrict__ kTs,
    const unsigned short* __restrict__ vS,
    const float* __restrict__ xg,
    float* out)
{
    __shared__ union {
        struct {
            short V[2][2][4096];         // [buf][grp][128 ch x 32 keys] swizzled
            short Pb[2][2][2][32 * 40];  // [iter-parity][grp][wq] 32q x 32k
        } s;
        struct {
            short Xst[64 * 128];         // preamble: X^T swizzled (= V[0] bytes)
            short Qs[64 * 128];          // preamble: Q^T swizzled (= V[1] bytes)
        } pre;
        float Ot[64 * 130];              // epilogue merge buffer
    } sm;
    __shared__ float Ls[2][2][32];       // [g][wq][row32] row-sums
    __shared__ float linvA[64];

    const int t    = threadIdx.x;
    const int w    = t >> 6;          // 0..7
    const int g    = w >> 2;          // key-group (2048-key half)
    const int wq   = (w >> 1) & 1;    // 32-query subtile
    const int h    = w & 1;           // QK: key-half; PV: channel-half
    const int sub  = w & 3;           // staging sub-tile
    const int lane = t & 63;
    const int l15  = lane & 15;
    const int quad = lane >> 4;

    const int b  = blockIdx.x & 7;               // XCD-pinned batch
    const int n0 = (blockIdx.x >> 3) * 64;
    const long base = (long)b * C_ * N_;

    // ================= preamble: compute Q tile in LDS =================
    #pragma unroll
    for (int it = 0; it < 4; ++it) {             // 512 threads: 4 float4 each
        const int c  = (t >> 4) + it * 32;
        const int n4 = (t & 15) * 4;
        const float4 xv = *(const float4*)(const void*)(xg + base + (long)c * N_ + n0 + n4);
        const int bc = c >> 3, cl = c & 7;
        sm.pre.Xst[(n4 + 0) * 128 + ((bc ^ ((n4 + 0) & 15)) << 3) + cl] = (short)f2b(xv.x);
        sm.pre.Xst[(n4 + 1) * 128 + ((bc ^ ((n4 + 1) & 15)) << 3) + cl] = (short)f2b(xv.y);
        sm.pre.Xst[(n4 + 2) * 128 + ((bc ^ ((n4 + 2) & 15)) << 3) + cl] = (short)f2b(xv.z);
        sm.pre.Xst[(n4 + 3) * 128 + ((bc ^ ((n4 + 3) & 15)) << 3) + cl] = (short)f2b(xv.w);
    }
    __syncthreads();
    {   // per-wave: 16 o-rows of Wq; 16 MFMA; scatter (acc+bq)*SCALE as bf16
        short8 aq[4];
        const int o = 16 * w + l15;
        #pragma unroll
        for (int ks = 0; ks < 4; ++ks) {
            const float4 a0 = *(const float4*)(const void*)(Wq + o * C_ + ks * 32 + quad * 8);
            const float4 a1 = *(const float4*)(const void*)(Wq + o * C_ + ks * 32 + quad * 8 + 4);
            union { unsigned int u[4]; short8 s; } pk;
            asm("v_cvt_pk_bf16_f32 %0, %1, %2" : "=v"(pk.u[0]) : "v"(a0.x), "v"(a0.y));
            asm("v_cvt_pk_bf16_f32 %0, %1, %2" : "=v"(pk.u[1]) : "v"(a0.z), "v"(a0.w));
            asm("v_cvt_pk_bf16_f32 %0, %1, %2" : "=v"(pk.u[2]) : "v"(a1.x), "v"(a1.y));
            asm("v_cvt_pk_bf16_f32 %0, %1, %2" : "=v"(pk.u[3]) : "v"(a1.z), "v"(a1.w));
            aq[ks] = pk.s;
        }
        f32x4 qa[4];
        #pragma unroll
        for (int nt = 0; nt < 4; ++nt) qa[nt] = (f32x4){0.f, 0.f, 0.f, 0.f};
        #pragma unroll
        for (int nt = 0; nt < 4; ++nt) {
            const int n = nt * 16 + l15;
            #pragma unroll
            for (int ks = 0; ks < 4; ++ks) {
                const short8 bx = *(const short8*)(const void*)(
                    sm.pre.Xst + n * 128 + (((ks * 4 + quad) ^ l15) << 3));
                qa[nt] = __builtin_amdgcn_mfma_f32_16x16x32_bf16(aq[ks], bx, qa[nt], 0, 0, 0);
            }
        }
        const float4 bb = *(const float4*)(const void*)(bq + 16 * w + quad * 4);
        #pragma unroll
        for (int r = 0; r < 4; ++r) {
            const int oo = 16 * w + quad * 4 + r;
            const float br = r == 0 ? bb.x : r == 1 ? bb.y : r == 2 ? bb.z : bb.w;
            #pragma unroll
            for (int nt = 0; nt < 4; ++nt) {
                const int n = nt * 16 + l15;
                sm.pre.Qs[n * 128 + (((oo >> 3) ^ (n & 15)) << 3) + (oo & 7)] =
                    (short)f2b((qa[nt][r] + br) * SCALE);
            }
        }
    }
    __syncthreads();

    // ---- Q B-frags from Qs (verbatim bx pattern; bit-identical to old q) ----
    short8 qf[2][4];
    #pragma unroll
    for (int qh = 0; qh < 2; ++qh)
        #pragma unroll
        for (int ks = 0; ks < 4; ++ks) {
            const int query = 32 * wq + qh * 16 + l15;   // local row, &15 == l15
            qf[qh][ks] = *(const short8*)(const void*)(
                sm.pre.Qs + query * 128 + (((ks * 4 + quad) ^ l15) << 3));
        }

    f32x4 acc[2][4];                  // [qh][ct]: 32q x 64c (channel-half h)
    #pragma unroll
    for (int qh = 0; qh < 2; ++qh)
        #pragma unroll
        for (int ct = 0; ct < 4; ++ct) acc[qh][ct] = (f32x4){0.f, 0.f, 0.f, 0.f};
    f32x4 accS[2];
    accS[0] = (f32x4){0.f, 0.f, 0.f, 0.f};
    accS[1] = (f32x4){0.f, 0.f, 0.f, 0.f};
    short8 ones;
    #pragma unroll
    for (int j = 0; j < 8; ++j) ones[j] = (short)0x3F80;   // bf16 1.0

    auto stageV = [&](int buf, int pair) {       // exactly 2 VMEM ops / lane
        const int mt = pair * 2 + g;
        char* lV = (char*)sm.s.V[buf][g];
        #pragma unroll
        for (int jj = 0; jj < 2; ++jj) {
            const int d  = sub * 2048 + jj * 1024;
            const int dv = d + lane * 16;
            const int c  = dv >> 6;
            gld_lds16((const char*)(vS + base + (long)c * N_ + mt * 32) + (dv & 63), lV + d);
        }
    };

    // ---- K direct global->reg: key = mt*32 + h*16 + l15, key&15 == l15 so
    // the baked-in kTs swizzle inverts with the same XOR as the LDS path ----
    const unsigned short* kp = kTs + base + (long)((g * 32 + h * 16 + l15) * C_);
    int ko[4];
    #pragma unroll
    for (int ks = 0; ks < 4; ++ks) ko[ks] = (((ks * 4 + quad) ^ l15) << 3);
    short8 kf[4];

    stageV(0, 0);
    #pragma unroll
    for (int ks = 0; ks < 4; ++ks) kf[ks] = *(const short8*)(const void*)(kp + ko[ks]);
    kp += 64 * C_;

    for (int i = 0; i < 64; ++i) {
        // ---- QK phase (registers only): P[32q][16k(h)] ----
        f32x4 sc[2];
        sc[0] = (f32x4){0.f, 0.f, 0.f, 0.f};
        sc[1] = (f32x4){0.f, 0.f, 0.f, 0.f};
        __builtin_amdgcn_s_setprio(1);
        #pragma unroll
        for (int qh = 0; qh < 2; ++qh)
            #pragma unroll
            for (int ks = 0; ks < 4; ++ks)
                sc[qh] = __builtin_amdgcn_mfma_f32_16x16x32_bf16(qf[qh][ks], kf[ks], sc[qh], 0, 0, 0);
        __builtin_amdgcn_s_setprio(0);

        // ---- prefetch kf(i+1): regs free, ~full iteration in flight ----
        if (i < 63) {
            #pragma unroll
            for (int ks = 0; ks < 4; ++ks) kf[ks] = *(const short8*)(const void*)(kp + ko[ks]);
            kp += 64 * C_;
        }

        // ---- softmax numerator -> P (iter-parity double buffer) ----
        short* Pw = sm.s.Pb[i & 1][g][wq];
        #pragma unroll
        for (int qh = 0; qh < 2; ++qh)
            #pragma unroll
            for (int r = 0; r < 4; ++r)
                Pw[(qh * 16 + quad * 4 + r) * 40 + h * 16 + l15] = (short)f2b(__expf(sc[qh][r]));

        // ---- single sync point: V(i) staged (vmcnt: kf(i+1) stays in
        // flight), own P writes drained, then barrier ----
        if (i < 63) asm volatile("s_waitcnt vmcnt(4)" ::: "memory");
        else        asm volatile("s_waitcnt vmcnt(0)" ::: "memory");
        asm volatile("s_waitcnt lgkmcnt(0)" ::: "memory");
        __builtin_amdgcn_s_barrier();
        __builtin_amdgcn_sched_barrier(0);

        // ---- V(i+1) stage: earliest legal point (all PV(i-1) reads of this
        // buffer completed before anyone passed B(i)) ----
        if (i < 63) stageV((i + 1) & 1, i + 1);

        // ---- PV phase: channel-half h, full 32-key P ----
        const short* Vb = sm.s.V[i & 1][g];
        const short8 pf0 = *(const short8*)(const void*)(Pw + (l15) * 40 + quad * 8);
        const short8 pf1 = *(const short8*)(const void*)(Pw + (16 + l15) * 40 + quad * 8);
        __builtin_amdgcn_s_setprio(1);
        if (h == 0) {                          // row-sums once per (g,wq)
            accS[0] = __builtin_amdgcn_mfma_f32_16x16x32_bf16(pf0, ones, accS[0], 0, 0, 0);
            accS[1] = __builtin_amdgcn_mfma_f32_16x16x32_bf16(pf1, ones, accS[1], 0, 0, 0);
        }
        #pragma unroll
        for (int ct = 0; ct < 4; ++ct) {
            const int ch = h * 64 + ct * 16 + l15;
            const short8 vf = *(const short8*)(const void*)(Vb + ch * 32 + ((quad ^ ((l15 >> 1) & 3)) << 3));
            acc[0][ct] = __builtin_amdgcn_mfma_f32_16x16x32_bf16(pf0, vf, acc[0][ct], 0, 0, 0);
            acc[1][ct] = __builtin_amdgcn_mfma_f32_16x16x32_bf16(pf1, vf, acc[1][ct], 0, 0, 0);
        }
        __builtin_amdgcn_s_setprio(0);
    }

    // ---- merge epilogue: Ot = O_g0 + O_g1; l via Ls; normalize + residual ----
    if (h == 0 && l15 == 0) {
        #pragma unroll
        for (int qh = 0; qh < 2; ++qh)
            #pragma unroll
            for (int r = 0; r < 4; ++r)
                Ls[g][wq][qh * 16 + quad * 4 + r] = accS[qh][r];
    }
    __syncthreads();                  // all PV reads done before Ot overlays LDS
    if (g == 0) {
        #pragma unroll
        for (int qh = 0; qh < 2; ++qh)
            #pragma unroll
            for (int ct = 0; ct < 4; ++ct)
                #pragma unroll
                for (int r = 0; r < 4; ++r)
                    sm.Ot[(32 * wq + qh * 16 + quad * 4 + r) * 130 + h * 64 + ct * 16 + l15] = acc[qh][ct][r];
    }
    __syncthreads();
    if (g == 1) {
        #pragma unroll
        for (int qh = 0; qh < 2; ++qh)
            #pragma unroll
            for (int ct = 0; ct < 4; ++ct)
                #pragma unroll
                for (int r = 0; r < 4; ++r)
                    sm.Ot[(32 * wq + qh * 16 + quad * 4 + r) * 130 + h * 64 + ct * 16 + l15] += acc[qh][ct][r];
    } else if (h == 0 && l15 == 0) {
        #pragma unroll
        for (int qh = 0; qh < 2; ++qh)
            #pragma unroll
            for (int r = 0; r < 4; ++r) {
                const int r32 = qh * 16 + quad * 4 + r;
                linvA[32 * wq + r32] = 1.0f / fmaxf(Ls[0][wq][r32] + Ls[1][wq][r32], 1e-20f);
            }
    }
    __syncthreads();

    const int c  = t >> 2;
    const int nh = (t & 3) * 16;
    const long gb = base + (long)c * N_ + n0 + nh;
    #pragma unroll
    for (int i = 0; i < 16; i += 4) {
        const float4 xs = *(const float4*)(const void*)(xg + gb + i);
        float4 rv;
        rv.x = sm.Ot[(nh + i + 0) * 130 + c] * linvA[nh + i + 0] + xs.x;
        rv.y = sm.Ot[(nh + i + 1) * 130 + c] * linvA[nh + i + 1] + xs.y;
        rv.z = sm.Ot[(nh + i + 2) * 130 + c] * linvA[nh + i + 2] + xs.z;
        rv.w = sm.Ot[(nh + i + 3) * 130 + c] * linvA[nh + i + 3] + xs.w;
        *(float4*)(void*)(out + gb + i) = rv;
    }
}

// ---------------------------------------------------------------------------
extern "C" void kernel_launch(void* const* d_in, const int* in_sizes, int n_in,
                              void* d_out, int out_size, void* d_ws, size_t ws_size,
                              hipStream_t stream) {
    const float* x  = (const float*)d_in[0];
    const float* Wq = (const float*)d_in[1];
    const float* bq = (const float*)d_in[2];
    const float* Wk = (const float*)d_in[3];
    const float* bk = (const float*)d_in[4];
    const float* Wv = (const float*)d_in[5];
    const float* bv = (const float*)d_in[6];
    float* out = (float*)d_out;

    const long BCN = (long)B_ * C_ * N_;                  // 4,194,304
    unsigned short* kTs = (unsigned short*)d_ws;          // [b][n][o'] bf16 swizzled
    unsigned short* vS  = kTs + BCN;                      // [b][o][n'] bf16 swizzled

    kv_mfma<<<512, 256, 0, stream>>>(x, Wk, bk, Wv, bv, kTs, vS);
    attn_mfma<<<B_ * (N_ / 64), 512, 0, stream>>>(Wq, bq, kTs, vS, x, out);
}